// Round 18
// baseline (138.530 us; speedup 1.0000x reference)
//
#include <hip/hip_runtime.h>
#include <hip/hip_bf16.h>
#include <math.h>

#define B_ 2
#define N_ 4096
#define C_ 256
#define H_ 8
#define K_ 32
#define NP_ (B_*N_)
#define CAPW 128

typedef __attribute__((ext_vector_type(8))) short bf16x8;
typedef __attribute__((ext_vector_type(4))) float f32x4;
typedef __attribute__((ext_vector_type(4))) unsigned short ushort4_t;

__device__ __forceinline__ float bf2f(unsigned short v){
    union { unsigned int u; float f; } x; x.u = ((unsigned int)v) << 16; return x.f;
}
__device__ __forceinline__ unsigned short f2bf(float f){
    union { float f; unsigned int u; } x; x.f = f;
    return (unsigned short)((x.u + 0x7FFFu + ((x.u >> 16) & 1u)) >> 16);
}
__device__ __forceinline__ unsigned int mono(float f){
    union { float f; unsigned int u; } x; x.f = f;
    return x.u ^ (0x80000000u | (unsigned int)((int)x.u >> 31));
}
__device__ __forceinline__ float unmono(unsigned int u){
    union { unsigned int u; float f; } x;
    x.u = (u & 0x80000000u) ? (u ^ 0x80000000u) : ~u;
    return x.f;
}
__device__ __forceinline__ void gload_lds16(const unsigned short* g, unsigned short* l){
    __builtin_amdgcn_global_load_lds(
        (const __attribute__((address_space(1))) unsigned int*)g,
        (__attribute__((address_space(3))) unsigned int*)l, 16, 0, 0);
}

// ================= mega-prologue: cvt | prep | morton | lnt | transposeB =========
__global__ __launch_bounds__(256) void k_pre(
    const float* __restrict__ s0, const float* __restrict__ s1,
    const float* __restrict__ s2, const float* __restrict__ s3,
    const float* __restrict__ s4, const float* __restrict__ s5,
    const float* __restrict__ s6, unsigned short* __restrict__ Wb,
    const float* __restrict__ xyzB, f32x4* __restrict__ PB,
    const float* __restrict__ xyzA, int* __restrict__ order,
    const float* __restrict__ featA, const float* __restrict__ lnw,
    const float* __restrict__ lnb, unsigned short* __restrict__ F,
    const float* __restrict__ featB, unsigned short* __restrict__ XBT)
{
    __shared__ __align__(16) char smem[35200];
    const int bid = blockIdx.x;
    const int tid = threadIdx.x;
    if (bid < 832){
        int i = (bid*256 + tid)*4;
        const float* s; int off;
        if (i < 327680){
            int seg = i >> 16;
            s = (seg==0)?s0:(seg==1)?s1:(seg==2)?s2:(seg==3)?s3:s4;
            off = i & 65535;
        } else if (i < 720896){
            s = s5; off = i - 327680;
        } else {
            s = s6; off = i - 720896;
        }
        f32x4 v = *(const f32x4*)(s + off);
        ushort4_t o;
        #pragma unroll
        for (int e = 0; e < 4; e++) o[e] = f2bf(v[e]);
        *(ushort4_t*)(Wb + i) = o;
    } else if (bid < 864){
        int i = (bid - 832)*256 + tid;
        float x = xyzB[i*3], y = xyzB[i*3+1], z = xyzB[i*3+2];
        f32x4 o;
        o[0] = -2.f*x; o[1] = -2.f*y; o[2] = -2.f*z;
        o[3] = x*x + y*y + z*z;
        PB[i] = o;
    } else if (bid < 866){
        unsigned int* hist = (unsigned int*)smem;
        unsigned int* wsum = (unsigned int*)(smem + 4096);
        const int b = bid - 864;
        const int wv = tid >> 6, lane = tid & 63;
        for (int i = tid; i < 1024; i += 256) hist[i] = 0u;
        __syncthreads();
        unsigned int code[16];
        #pragma unroll
        for (int i = 0; i < 16; i++){
            const int n = tid + i*256;
            const float* pp = xyzA + (size_t)((b<<12) + n)*3;
            int qx = (int)fminf(fmaxf((pp[0] + 5.f)*1.6f, 0.f), 15.f);
            int qy = (int)fminf(fmaxf((pp[1] + 5.f)*0.8f, 0.f), 7.f);
            int qz = (int)fminf(fmaxf((pp[2] + 5.f)*0.8f, 0.f), 7.f);
            unsigned int c = (unsigned int)((qx & 1) | ((qz & 1) << 1) | ((qy & 1) << 2)
                           | (((qx >> 1) & 1) << 3) | (((qz >> 1) & 1) << 4) | (((qy >> 1) & 1) << 5)
                           | (((qx >> 2) & 1) << 6) | (((qz >> 2) & 1) << 7) | (((qy >> 2) & 1) << 8)
                           | (((qx >> 3) & 1) << 9));
            code[i] = c;
            atomicAdd(&hist[c], 1u);
        }
        __syncthreads();
        unsigned int loc[4], t4 = 0;
        #pragma unroll
        for (int j = 0; j < 4; j++){ loc[j] = hist[tid*4 + j]; t4 += loc[j]; }
        unsigned int sc = t4;
        #pragma unroll
        for (int off = 1; off < 64; off <<= 1){
            unsigned int o = __shfl_up(sc, off, 64);
            if (lane >= off) sc += o;
        }
        if (lane == 63) wsum[wv] = sc;
        __syncthreads();
        unsigned int wb = 0;
        #pragma unroll
        for (int j = 0; j < 4; j++) if (j < wv) wb += wsum[j];
        unsigned int base = wb + sc - t4;
        #pragma unroll
        for (int j = 0; j < 4; j++){ hist[tid*4 + j] = base; base += loc[j]; }
        __syncthreads();
        #pragma unroll
        for (int i = 0; i < 16; i++){
            const int n = tid + i*256;
            unsigned int pos = atomicAdd(&hist[code[i]], 1u);
            order[(b<<12) + pos] = (b<<12) | n;
        }
    } else if (bid < 1122){
        float (*tile)[257] = (float(*)[257])smem;
        float (*ps)[32]    = (float(*)[32])(smem + 32896);
        float (*pq)[32]    = (float(*)[32])(smem + 33920);
        float (*st)[32]    = (float(*)[32])(smem + 34944);
        const int nx = tid & 31, cy = tid >> 5;
        const int pbase = (bid - 866) * 32;
        const int b = pbase >> 12, n0 = pbase & 4095;
        const float* sp = featA + (size_t)b*C_*N_ + n0;
        #pragma unroll 4
        for (int it = 0; it < 32; it++){
            int c = cy + it*8;
            tile[nx][c] = sp[(size_t)c*N_ + nx];
        }
        __syncthreads();
        {
            float s = 0.f, q = 0.f;
            #pragma unroll 8
            for (int i = 0; i < 32; i++){
                int cc = cy*32 + ((i + cy) & 31);
                float x = tile[nx][cc];
                s += x; q = fmaf(x, x, q);
            }
            ps[cy][nx] = s; pq[cy][nx] = q;
        }
        __syncthreads();
        if (tid < 32){
            float S = 0.f, Q = 0.f;
            #pragma unroll
            for (int j = 0; j < 8; j++){ S += ps[j][tid]; Q += pq[j][tid]; }
            float m = S*(1.f/256.f);
            float v = Q*(1.f/256.f) - m*m;
            st[0][tid] = m; st[1][tid] = rsqrtf(v + 1e-5f);
        }
        __syncthreads();
        const int p = pbase + nx;
        const float m = st[0][nx], r = st[1][nx];
        #pragma unroll
        for (int j = 0; j < 4; j++){
            bf16x8 ob;
            #pragma unroll
            for (int e = 0; e < 8; e++){
                int c = cy*32 + j*8 + e;
                ob[e] = (short)f2bf((tile[nx][c]-m)*r*lnw[c] + lnb[c]);
            }
            *(bf16x8*)(F + (size_t)p*768 + cy*32 + j*8) = ob;
        }
    } else {
        float (*tile)[65] = (float(*)[65])smem;
        const int idx = bid - 1122;
        const int x = idx & 63, y = (idx >> 6) & 3, z = idx >> 8;
        const int n0 = x*64, c0 = y*64;
        const int tx = tid & 63, ty = tid >> 6;
        const float* sp = featB + (size_t)z*C_*N_;
        #pragma unroll
        for (int i = 0; i < 16; i++){
            int cr = ty + i*4;
            tile[cr][tx] = sp[(size_t)(c0+cr)*N_ + n0 + tx];
        }
        __syncthreads();
        const int c = c0 + tx;
        #pragma unroll
        for (int i = 0; i < 16; i++){
            int nr = ty + i*4;
            int p = (z<<12) + n0 + nr;
            XBT[(size_t)p*256 + c] = f2bf(tile[tx][nr]);
        }
    }
}

// ---------------- KNN: 4 queries per wave, float-domain select ----------------
__global__ __launch_bounds__(256) void k_knn(const float* __restrict__ xyzA,
        const f32x4* __restrict__ PB, int* __restrict__ knn){
    const int wv = threadIdx.x >> 6, lane = threadIdx.x & 63;
    const int q0 = blockIdx.x*16 + wv*4;       // 512 blocks x 4 waves x 4 queries
    const int b = q0 >> 12;
    const f32x4* pb = PB + ((size_t)b << 12);
    float axq[4], ayq[4], azq[4];
    #pragma unroll
    for (int qq = 0; qq < 4; qq++){
        axq[qq] = xyzA[(size_t)(q0+qq)*3];
        ayq[qq] = xyzA[(size_t)(q0+qq)*3+1];
        azq[qq] = xyzA[(size_t)(q0+qq)*3+2];
    }

    // ---- pass 1: per-lane minima for the 4 queries ----
    float dm[4] = {3.4e38f, 3.4e38f, 3.4e38f, 3.4e38f};
    int   mi[4] = {0,0,0,0};
    #pragma unroll 4
    for (int i = 0; i < 64; i++){
        const int m = i*64 + lane;
        f32x4 c = pb[m];
        #pragma unroll
        for (int qq = 0; qq < 4; qq++){
            float d = fmaf(axq[qq], c[0], fmaf(ayq[qq], c[1], fmaf(azq[qq], c[2], c[3])));
            if (d < dm[qq]){ dm[qq] = d; mi[qq] = m; }
        }
    }
    // ---- rank-31 threshold per query (u64-exact, interleaved shuffles) ----
    unsigned long long key[4];
    #pragma unroll
    for (int qq = 0; qq < 4; qq++)
        key[qq] = (((unsigned long long)mono(dm[qq])) << 12) | (unsigned int)mi[qq];
    unsigned int rk[4] = {0,0,0,0};
    for (int j = 0; j < 64; j++){
        #pragma unroll
        for (int qq = 0; qq < 4; qq++){
            unsigned long long o = __shfl(key[qq], j, 64);
            rk[qq] += (o < key[qq]) ? 1u : 0u;
        }
    }
    unsigned long long sel[4];
    #pragma unroll
    for (int qq = 0; qq < 4; qq++) sel[qq] = (rk[qq] == 31u) ? key[qq] : ~0ull;
    #pragma unroll
    for (int off = 32; off; off >>= 1){
        #pragma unroll
        for (int qq = 0; qq < 4; qq++){
            unsigned long long o = __shfl_xor(sel[qq], off, 64);
            sel[qq] = o < sel[qq] ? o : sel[qq];
        }
    }
    float vf[4];
    #pragma unroll
    for (int qq = 0; qq < 4; qq++) vf[qq] = unmono((unsigned int)(sel[qq] >> 12));

    // ---- pass 2: gather candidates per query slab ----
    __shared__ unsigned long long cand[16][CAPW];   // 16 KB
    __shared__ unsigned int cnt[16];
    if (lane < 4) cnt[wv*4 + lane] = 0u;
    #pragma unroll 4
    for (int i = 0; i < 64; i++){
        const int m = i*64 + lane;
        f32x4 c = pb[m];
        #pragma unroll
        for (int qq = 0; qq < 4; qq++){
            float d = fmaf(axq[qq], c[0], fmaf(ayq[qq], c[1], fmaf(azq[qq], c[2], c[3])));
            if (d <= vf[qq]){
                unsigned int slot = atomicAdd(&cnt[wv*4 + qq], 1u);
                if (slot < CAPW)
                    cand[wv*4 + qq][slot] = (((unsigned long long)mono(d)) << 12) | (unsigned int)m;
            }
        }
    }
    // ---- exact rank among candidates per query ----
    #pragma unroll
    for (int qq = 0; qq < 4; qq++){
        const int slab = wv*4 + qq;
        const unsigned int C = cnt[slab];
        if (C <= CAPW){
            for (unsigned int i = lane; i < C; i += 64){
                unsigned long long mk = cand[slab][i];
                unsigned int rank = 0;
                for (unsigned int j = 0; j < C; j++) rank += (cand[slab][j] < mk) ? 1u : 0u;
                if (rank < K_) knn[(size_t)(q0+qq)*K_ + rank] = (int)(mk & 0xFFFull);
            }
        } else {
            // correctness-only fallback: ascending threshold walk (stateless, exact)
            unsigned long long last = 0ull;
            for (int it = 0; it < K_; it++){
                unsigned long long cm = ~0ull;
                #pragma unroll 4
                for (int i = 0; i < 64; i++){
                    const int m = i*64 + lane;
                    f32x4 c = pb[m];
                    float d = fmaf(axq[qq], c[0], fmaf(ayq[qq], c[1], fmaf(azq[qq], c[2], c[3])));
                    unsigned long long kk2 = (((unsigned long long)mono(d)) << 12) | (unsigned int)m;
                    if (kk2 > last && kk2 < cm) cm = kk2;
                }
                #pragma unroll
                for (int off = 32; off; off >>= 1){
                    unsigned long long o = __shfl_xor(cm, off, 64);
                    cm = o < cm ? o : cm;
                }
                if (lane == 0) knn[(size_t)(q0+qq)*K_ + it] = (int)(cm & 0xFFFull);
                last = cm;
            }
        }
    }
}

// ---------------- MFMA GEMM body: 128x64 tile, BK=32, gload_lds double buffer ----
template<int MODE>
__device__ __forceinline__ void gemm_body(
    const unsigned short* __restrict__ X, int ldx,
    const unsigned short* __restrict__ W, int Kin,
    const float* __restrict__ e0, const float* __restrict__ e1, const float* __restrict__ e2,
    unsigned short* __restrict__ Y, int ldy,
    const float* __restrict__ resid, float* __restrict__ out,
    unsigned short (*As)[128*32], unsigned short (*Bs)[64*32], int bx, int by)
{
    const int tid = threadIdx.x, wid = tid >> 6, lane = tid & 63;
    const int lr = lane & 15, lg = lane >> 4;
    const int m0 = bx*128, n0 = by*64;
    const int lrow = lane >> 2, lcol = (lane & 3)*8;

    const unsigned short* Ag0 = X + (size_t)(m0 + wid*32 + lrow)*ldx + lcol;
    const unsigned short* Ag1 = X + (size_t)(m0 + wid*32 + 16 + lrow)*ldx + lcol;
    const unsigned short* Bg0 = W + (size_t)(n0 + wid*16 + lrow)*Kin + lcol;

    f32x4 acc[2][4] = {};
    const int NT = Kin >> 5;
    int buf = 0;
    gload_lds16(Ag0, &As[0][(wid*32)*32]);
    gload_lds16(Ag1, &As[0][(wid*32+16)*32]);
    gload_lds16(Bg0, &Bs[0][(wid*16)*32]);
    __syncthreads();
    for (int kt = 0; kt < NT; kt++){
        if (kt + 1 < NT){
            const int k = (kt+1)*32;
            gload_lds16(Ag0 + k, &As[buf^1][(wid*32)*32]);
            gload_lds16(Ag1 + k, &As[buf^1][(wid*32+16)*32]);
            gload_lds16(Bg0 + k, &Bs[buf^1][(wid*16)*32]);
        }
        bf16x8 a[2], b[4];
        #pragma unroll
        for (int mi = 0; mi < 2; mi++)
            a[mi] = *(const bf16x8*)&As[buf][(wid*32 + mi*16 + lr)*32 + lg*8];
        #pragma unroll
        for (int ni = 0; ni < 4; ni++)
            b[ni] = *(const bf16x8*)&Bs[buf][(ni*16 + lr)*32 + lg*8];
        #pragma unroll
        for (int mi = 0; mi < 2; mi++){
            #pragma unroll
            for (int ni = 0; ni < 4; ni++)
                acc[mi][ni] = __builtin_amdgcn_mfma_f32_16x16x32_bf16(a[mi], b[ni], acc[mi][ni], 0, 0, 0);
        }
        __syncthreads();
        buf ^= 1;
    }
    #pragma unroll
    for (int mi = 0; mi < 2; mi++){
        const int pbase = m0 + wid*32 + mi*16 + lg*4;
        #pragma unroll
        for (int ni = 0; ni < 4; ni++){
            const int o = n0 + ni*16 + lr;
            if (MODE == 0){
                const float* bp = (o < 256) ? e0 : ((o < 512) ? e1 : e2);
                float bias = bp[o & 255];
                #pragma unroll
                for (int r = 0; r < 4; r++)
                    Y[(size_t)(pbase + r)*ldy + o] = f2bf(acc[mi][ni][r] + bias);
            } else if (MODE == 1){
                float sc = e0[o] * 0.9999950000374997f;
                float sh = e1[o];
                #pragma unroll
                for (int r = 0; r < 4; r++){
                    float vv = fmaf(acc[mi][ni][r], sc, sh);
                    Y[(size_t)(pbase + r)*ldy + o] = f2bf(fmaxf(vv, 0.f));
                }
            } else {
                float bias = e0[o];
                const int b = pbase >> 12, nn = pbase & 4095;
                const size_t adr = ((size_t)b*C_ + o)*N_ + nn;
                f32x4 rv = *(const f32x4*)(resid + adr);
                f32x4 ov;
                #pragma unroll
                for (int r = 0; r < 4; r++) ov[r] = acc[mi][ni][r] + bias + rv[r];
                *(f32x4*)(out + adr) = ov;
            }
        }
    }
}

__global__ __launch_bounds__(256) void k_proj(
    const unsigned short* __restrict__ F, const unsigned short* __restrict__ XBT,
    const unsigned short* __restrict__ WQcat, const unsigned short* __restrict__ WKVD,
    const float* __restrict__ bq, const float* __restrict__ bqd,
    const float* __restrict__ bk, const float* __restrict__ bv, const float* __restrict__ bkd,
    unsigned short* __restrict__ QQ, unsigned short* __restrict__ KVD)
{
    __shared__ __align__(16) unsigned short As[2][128*32];
    __shared__ __align__(16) unsigned short Bs[2][64*32];
    if (blockIdx.y < 8)
        gemm_body<0>(F, 768, WQcat, 256, bq, bqd, nullptr, QQ, 512, nullptr, nullptr,
                     As, Bs, blockIdx.x, blockIdx.y);
    else
        gemm_body<0>(XBT, 256, WKVD, 256, bk, bv, bkd, KVD, 768, nullptr, nullptr,
                     As, Bs, blockIdx.x, blockIdx.y - 8);
}

template<int MODE>
__global__ __launch_bounds__(256) void k_gemm(
    const unsigned short* __restrict__ X, int ldx,
    const unsigned short* __restrict__ W, int Kin,
    const float* __restrict__ e0, const float* __restrict__ e1, const float* __restrict__ e2,
    unsigned short* __restrict__ Y, int ldy,
    const float* __restrict__ resid, float* __restrict__ out)
{
    __shared__ __align__(16) unsigned short As[2][128*32];
    __shared__ __align__(16) unsigned short Bs[2][64*32];
    gemm_body<MODE>(X, ldx, W, Kin, e0, e1, e2, Y, ldy, resid, out,
                    As, Bs, blockIdx.x, blockIdx.y);
}

// ---------------- dual-path neighbor attention: row-cooperative gathers -----------
// (round-16 version, verbatim: direct-diff dist, scalar unpack — known good)
__global__ __launch_bounds__(128) void k_attn(
    const unsigned short* __restrict__ QQ, const unsigned short* __restrict__ KVD,
    const int* __restrict__ KNN, const int* __restrict__ order,
    const float* __restrict__ lnsw, const float* __restrict__ lnsb,
    const float* __restrict__ lndw, const float* __restrict__ lndb,
    unsigned short* __restrict__ F)
{
    __shared__ int   idx_l[2][32];
    __shared__ float part_l[2][4];

    const int tid = threadIdx.x;
    const int wh = tid >> 6, lane = tid & 63;
    const int bid = blockIdx.x;
    const int xcd = bid & 7, ib = bid >> 3;
    const int batch = xcd & 1, quarter = xcd >> 1;
    const int p = order[(batch << 12) + quarter*1024 + ib];
    const int b = batch;

    if (lane < 32) idx_l[wh][lane] = KNN[(size_t)p*K_ + lane];

    const int tq = lane >> 4, c = lane & 15;

    float qsf[8], qdf[8];
    {
        const unsigned short* qrow = QQ + (size_t)p*512 + wh*128 + c*8;
        bf16x8 qs8 = *(const bf16x8*)(qrow);
        bf16x8 qd8 = *(const bf16x8*)(qrow + 256);
        #pragma unroll
        for (int e = 0; e < 8; e++){
            qsf[e] = bf2f((unsigned short)qs8[e]);
            qdf[e] = bf2f((unsigned short)qd8[e]);
        }
    }
    const unsigned short* KB = KVD + (size_t)(b << 12)*768;
    int nbt[8];
    #pragma unroll
    for (int i = 0; i < 8; i++) nbt[i] = idx_l[wh][tq + i*4];

    float s[8];
    {
        bf16x8 kx[8];
        #pragma unroll
        for (int i = 0; i < 8; i++)
            kx[i] = *(const bf16x8*)(KB + (size_t)nbt[i]*768 + wh*128 + c*8);
        #pragma unroll
        for (int i = 0; i < 8; i++){
            float a = 0.f;
            #pragma unroll
            for (int e = 0; e < 8; e++)
                a = fmaf(qsf[e], bf2f((unsigned short)kx[i][e]), a);
            s[i] = a;
        }
    }
    float t[8];
    {
        bf16x8 dx[8];
        #pragma unroll
        for (int i = 0; i < 8; i++)
            dx[i] = *(const bf16x8*)(KB + (size_t)nbt[i]*768 + 512 + wh*128 + c*8);
        #pragma unroll
        for (int i = 0; i < 8; i++){
            float a = 0.f;
            #pragma unroll
            for (int e = 0; e < 8; e++){
                float df = qdf[e] - bf2f((unsigned short)dx[i][e]);
                a = fmaf(df, df, a);
            }
            t[i] = a;
        }
    }
    bf16x8 vx[8];
    #pragma unroll
    for (int i = 0; i < 8; i++)
        vx[i] = *(const bf16x8*)(KB + (size_t)nbt[i]*768 + 256 + wh*128 + c*8);

    #pragma unroll
    for (int i = 0; i < 8; i++){
        s[i] += __shfl_xor(s[i], 1, 64); s[i] += __shfl_xor(s[i], 2, 64);
        t[i] += __shfl_xor(t[i], 1, 64); t[i] += __shfl_xor(t[i], 2, 64);
    }
    float sim[8], dist[8];
    #pragma unroll
    for (int i = 0; i < 8; i++){
        sim[i]  = s[i] * 0.17677669529663687f;   // 1/sqrt(32)
        dist[i] = sqrtf(t[i]);
    }
    float m1 = sim[0], m2 = dist[0];
    #pragma unroll
    for (int i = 1; i < 8; i++){ m1 = fmaxf(m1, sim[i]); m2 = fmaxf(m2, dist[i]); }
    m1 = fmaxf(m1, __shfl_xor(m1, 16, 64)); m1 = fmaxf(m1, __shfl_xor(m1, 32, 64));
    m2 = fmaxf(m2, __shfl_xor(m2, 16, 64)); m2 = fmaxf(m2, __shfl_xor(m2, 32, 64));
    float e1[8], e2[8], s1 = 0.f, s2 = 0.f;
    #pragma unroll
    for (int i = 0; i < 8; i++){
        e1[i] = __expf(sim[i] - m1);  s1 += e1[i];
        e2[i] = __expf(dist[i] - m2); s2 += e2[i];
    }
    s1 += __shfl_xor(s1, 16, 64); s1 += __shfl_xor(s1, 32, 64);
    s2 += __shfl_xor(s2, 16, 64); s2 += __shfl_xor(s2, 32, 64);
    const float r1i = 1.f / s1, r2i = 1.f / s2;

    float cs[8] = {0,0,0,0,0,0,0,0}, cd[8] = {0,0,0,0,0,0,0,0};
    #pragma unroll
    for (int i = 0; i < 8; i++){
        const float w1 = e1[i] * r1i;
        const float w2 = e2[i] * r2i;
        #pragma unroll
        for (int e = 0; e < 8; e++){
            float vf = bf2f((unsigned short)vx[i][e]);
            cs[e] = fmaf(w1, vf, cs[e]);
            cd[e] = fmaf(w2, vf, cd[e]);
        }
    }
    #pragma unroll
    for (int e = 0; e < 8; e++){
        cs[e] += __shfl_xor(cs[e], 16, 64); cs[e] += __shfl_xor(cs[e], 32, 64);
        cd[e] += __shfl_xor(cd[e], 16, 64); cd[e] += __shfl_xor(cd[e], 32, 64);
    }
    float s1n = 0.f, q1n = 0.f, s2n = 0.f, q2n = 0.f;
    #pragma unroll
    for (int e = 0; e < 8; e++){
        s1n += cs[e]; q1n = fmaf(cs[e], cs[e], q1n);
        s2n += cd[e]; q2n = fmaf(cd[e], cd[e], q2n);
    }
    #pragma unroll
    for (int off = 1; off < 16; off <<= 1){
        s1n += __shfl_xor(s1n, off, 64); q1n += __shfl_xor(q1n, off, 64);
        s2n += __shfl_xor(s2n, off, 64); q2n += __shfl_xor(q2n, off, 64);
    }
    if (lane == 0){
        part_l[wh][0] = s1n; part_l[wh][1] = q1n;
        part_l[wh][2] = s2n; part_l[wh][3] = q2n;
    }
    __syncthreads();
    const float S1 = s1n + part_l[wh^1][0];
    const float Q1 = q1n + part_l[wh^1][1];
    const float S2 = s2n + part_l[wh^1][2];
    const float Q2 = q2n + part_l[wh^1][3];
    const float mm1 = S1*(1.f/256.f), mm2 = S2*(1.f/256.f);
    const float rr1 = rsqrtf(Q1*(1.f/256.f) - mm1*mm1 + 1e-5f);
    const float rr2 = rsqrtf(Q2*(1.f/256.f) - mm2*mm2 + 1e-5f);

    if (tq == 0){
        bf16x8 ob;
        #pragma unroll
        for (int e = 0; e < 8; e++){
            const int cg = wh*128 + c*8 + e;
            ob[e] = (short)f2bf((cs[e]-mm1)*rr1*lnsw[cg] + lnsb[cg]);
        }
        *(bf16x8*)(F + (size_t)p*768 + 256 + wh*128 + c*8) = ob;
    } else if (tq == 1){
        bf16x8 ob;
        #pragma unroll
        for (int e = 0; e < 8; e++){
            const int cg = wh*128 + c*8 + e;
            ob[e] = (short)f2bf((cd[e]-mm2)*rr2*lndw[cg] + lndb[cg]);
        }
        *(bf16x8*)(F + (size_t)p*768 + 512 + wh*128 + c*8) = ob;
    }
}

extern "C" void kernel_launch(void* const* d_in, const int* in_sizes, int n_in,
                              void* d_out, int out_size, void* d_ws, size_t ws_size,
                              hipStream_t stream)
{
    const float* xyzA   = (const float*)d_in[0];
    const float* xyzB   = (const float*)d_in[1];
    const float* featA  = (const float*)d_in[2];
    const float* featB  = (const float*)d_in[3];
    const float* ln_in_w= (const float*)d_in[4];
    const float* ln_in_b= (const float*)d_in[5];
    const float* wq  = (const float*)d_in[6];
    const float* bq  = (const float*)d_in[7];
    const float* wk  = (const float*)d_in[8];
    const float* bk  = (const float*)d_in[9];
    const float* wv  = (const float*)d_in[10];
    const float* bv  = (const float*)d_in[11];
    const float* wqd = (const float*)d_in[12];
    const float* bqd = (const float*)d_in[13];
    const float* wkd = (const float*)d_in[14];
    const float* bkd = (const float*)d_in[15];
    const float* lnsw = (const float*)d_in[16];
    const float* lnsb = (const float*)d_in[17];
    const float* lndw = (const float*)d_in[18];
    const float* lndb = (const float*)d_in[19];
    const float* fw1 = (const float*)d_in[20];
    const float* bng = (const float*)d_in[21];
    const float* bnb = (const float*)d_in[22];
    const float* fw2 = (const float*)d_in[23];
    const float* fb2 = (const float*)d_in[24];
    float* out = (float*)d_out;
    char* ws = (char*)d_ws;

    unsigned short* F    = (unsigned short*)(ws + 0);          // 8192*768 bf16
    unsigned short* XBT  = (unsigned short*)(ws + 12582912);   // 8192*256
    unsigned short* QQ   = (unsigned short*)(ws + 16777216);   // 8192*512
    unsigned short* KVD  = (unsigned short*)(ws + 25165824);   // 8192*768
    unsigned short* Y1   = (unsigned short*)(ws + 37748736);   // 8192*512 ; PB earlier
    f32x4*          PB   = (f32x4*)(ws + 37748736);            // dead before fus1
    int*            KNNi = (int*)(ws + 46137344);              // 8192*32
    int*            ORD  = (int*)(ws + 47185920);              // 8192*4
    unsigned short* Wb   = (unsigned short*)(ws + 47251456);   // 851968 bf16
    unsigned short* WQcat = Wb;                // 512x256
    unsigned short* WKVD  = Wb + 131072;       // 768x256
    unsigned short* W1b   = Wb + 327680;       // 512x768
    unsigned short* W2b   = Wb + 720896;       // 256x512

    k_pre<<<1634, 256, 0, stream>>>(wq, wqd, wk, wv, wkd, fw1, fw2, Wb,
                                    xyzB, PB, xyzA, ORD,
                                    featA, ln_in_w, ln_in_b, F, featB, XBT);
    k_knn<<<512, 256, 0, stream>>>(xyzA, PB, KNNi);

    k_proj<<<dim3(64,20), 256, 0, stream>>>(F, XBT, WQcat, WKVD, bq, bqd, bk, bv, bkd, QQ, KVD);

    k_attn<<<8192, 128, 0, stream>>>(QQ, KVD, KNNi, ORD, lnsw, lnsb, lndw, lndb, F);

    k_gemm<1><<<dim3(64,8), 256, 0, stream>>>(F,  768, W1b, 768, bng, bnb, nullptr, Y1, 512, nullptr, nullptr);
    k_gemm<2><<<dim3(64,4), 256, 0, stream>>>(Y1, 512, W2b, 512, fb2, nullptr, nullptr, nullptr, 0, featA, out);
}

// Round 19
// 128.562 us; speedup vs baseline: 1.0775x; 1.0775x over previous
//
#include <hip/hip_runtime.h>
#include <hip/hip_bf16.h>
#include <math.h>

#define B_ 2
#define N_ 4096
#define C_ 256
#define H_ 8
#define K_ 32
#define NP_ (B_*N_)
#define CAPW 256

typedef __attribute__((ext_vector_type(8))) short bf16x8;
typedef __attribute__((ext_vector_type(4))) float f32x4;
typedef __attribute__((ext_vector_type(4))) unsigned short ushort4_t;

__device__ __forceinline__ float bf2f(unsigned short v){
    union { unsigned int u; float f; } x; x.u = ((unsigned int)v) << 16; return x.f;
}
__device__ __forceinline__ unsigned short f2bf(float f){
    union { float f; unsigned int u; } x; x.f = f;
    return (unsigned short)((x.u + 0x7FFFu + ((x.u >> 16) & 1u)) >> 16);
}
__device__ __forceinline__ unsigned int mono(float f){
    union { float f; unsigned int u; } x; x.f = f;
    return x.u ^ (0x80000000u | (unsigned int)((int)x.u >> 31));
}
__device__ __forceinline__ float unmono(unsigned int u){
    union { unsigned int u; float f; } x;
    x.u = (u & 0x80000000u) ? (u ^ 0x80000000u) : ~u;
    return x.f;
}
__device__ __forceinline__ void gload_lds16(const unsigned short* g, unsigned short* l){
    __builtin_amdgcn_global_load_lds(
        (const __attribute__((address_space(1))) unsigned int*)g,
        (__attribute__((address_space(3))) unsigned int*)l, 16, 0, 0);
}

// ================= mega-prologue: cvt | prep | morton | lnt | transposeB =========
// ranges: [0,832) cvt, [832,864) prep, [864,866) morton, [866,1122) lnt,
//         [1122,1378) transposeB (lnt-style vectorized stores)
__global__ __launch_bounds__(256) void k_pre(
    const float* __restrict__ s0, const float* __restrict__ s1,
    const float* __restrict__ s2, const float* __restrict__ s3,
    const float* __restrict__ s4, const float* __restrict__ s5,
    const float* __restrict__ s6, unsigned short* __restrict__ Wb,
    const float* __restrict__ xyzB, f32x4* __restrict__ PB,
    const float* __restrict__ xyzA, int* __restrict__ order,
    const float* __restrict__ featA, const float* __restrict__ lnw,
    const float* __restrict__ lnb, unsigned short* __restrict__ F,
    const float* __restrict__ featB, unsigned short* __restrict__ XBT)
{
    __shared__ __align__(16) char smem[35200];
    const int bid = blockIdx.x;
    const int tid = threadIdx.x;
    if (bid < 832){
        int i = (bid*256 + tid)*4;
        const float* s; int off;
        if (i < 327680){
            int seg = i >> 16;
            s = (seg==0)?s0:(seg==1)?s1:(seg==2)?s2:(seg==3)?s3:s4;
            off = i & 65535;
        } else if (i < 720896){
            s = s5; off = i - 327680;
        } else {
            s = s6; off = i - 720896;
        }
        f32x4 v = *(const f32x4*)(s + off);
        ushort4_t o;
        #pragma unroll
        for (int e = 0; e < 4; e++) o[e] = f2bf(v[e]);
        *(ushort4_t*)(Wb + i) = o;
    } else if (bid < 864){
        int i = (bid - 832)*256 + tid;
        float x = xyzB[i*3], y = xyzB[i*3+1], z = xyzB[i*3+2];
        f32x4 o;
        o[0] = -2.f*x; o[1] = -2.f*y; o[2] = -2.f*z;
        o[3] = x*x + y*y + z*z;
        PB[i] = o;
    } else if (bid < 866){
        unsigned int* hist = (unsigned int*)smem;
        unsigned int* wsum = (unsigned int*)(smem + 4096);
        const int b = bid - 864;
        const int wv = tid >> 6, lane = tid & 63;
        for (int i = tid; i < 1024; i += 256) hist[i] = 0u;
        __syncthreads();
        unsigned int code[16];
        #pragma unroll
        for (int i = 0; i < 16; i++){
            const int n = tid + i*256;
            const float* pp = xyzA + (size_t)((b<<12) + n)*3;
            int qx = (int)fminf(fmaxf((pp[0] + 5.f)*1.6f, 0.f), 15.f);
            int qy = (int)fminf(fmaxf((pp[1] + 5.f)*0.8f, 0.f), 7.f);
            int qz = (int)fminf(fmaxf((pp[2] + 5.f)*0.8f, 0.f), 7.f);
            unsigned int c = (unsigned int)((qx & 1) | ((qz & 1) << 1) | ((qy & 1) << 2)
                           | (((qx >> 1) & 1) << 3) | (((qz >> 1) & 1) << 4) | (((qy >> 1) & 1) << 5)
                           | (((qx >> 2) & 1) << 6) | (((qz >> 2) & 1) << 7) | (((qy >> 2) & 1) << 8)
                           | (((qx >> 3) & 1) << 9));
            code[i] = c;
            atomicAdd(&hist[c], 1u);
        }
        __syncthreads();
        unsigned int loc[4], t4 = 0;
        #pragma unroll
        for (int j = 0; j < 4; j++){ loc[j] = hist[tid*4 + j]; t4 += loc[j]; }
        unsigned int sc = t4;
        #pragma unroll
        for (int off = 1; off < 64; off <<= 1){
            unsigned int o = __shfl_up(sc, off, 64);
            if (lane >= off) sc += o;
        }
        if (lane == 63) wsum[wv] = sc;
        __syncthreads();
        unsigned int wb = 0;
        #pragma unroll
        for (int j = 0; j < 4; j++) if (j < wv) wb += wsum[j];
        unsigned int base = wb + sc - t4;
        #pragma unroll
        for (int j = 0; j < 4; j++){ hist[tid*4 + j] = base; base += loc[j]; }
        __syncthreads();
        #pragma unroll
        for (int i = 0; i < 16; i++){
            const int n = tid + i*256;
            unsigned int pos = atomicAdd(&hist[code[i]], 1u);
            order[(b<<12) + pos] = (b<<12) | n;
        }
    } else if (bid < 1122){
        float (*tile)[257] = (float(*)[257])smem;
        float (*ps)[32]    = (float(*)[32])(smem + 32896);
        float (*pq)[32]    = (float(*)[32])(smem + 33920);
        float (*st)[32]    = (float(*)[32])(smem + 34944);
        const int nx = tid & 31, cy = tid >> 5;
        const int pbase = (bid - 866) * 32;
        const int b = pbase >> 12, n0 = pbase & 4095;
        const float* sp = featA + (size_t)b*C_*N_ + n0;
        #pragma unroll 4
        for (int it = 0; it < 32; it++){
            int c = cy + it*8;
            tile[nx][c] = sp[(size_t)c*N_ + nx];
        }
        __syncthreads();
        {
            float s = 0.f, q = 0.f;
            #pragma unroll 8
            for (int i = 0; i < 32; i++){
                int cc = cy*32 + ((i + cy) & 31);
                float x = tile[nx][cc];
                s += x; q = fmaf(x, x, q);
            }
            ps[cy][nx] = s; pq[cy][nx] = q;
        }
        __syncthreads();
        if (tid < 32){
            float S = 0.f, Q = 0.f;
            #pragma unroll
            for (int j = 0; j < 8; j++){ S += ps[j][tid]; Q += pq[j][tid]; }
            float m = S*(1.f/256.f);
            float v = Q*(1.f/256.f) - m*m;
            st[0][tid] = m; st[1][tid] = rsqrtf(v + 1e-5f);
        }
        __syncthreads();
        const int p = pbase + nx;
        const float m = st[0][nx], r = st[1][nx];
        #pragma unroll
        for (int j = 0; j < 4; j++){
            bf16x8 ob;
            #pragma unroll
            for (int e = 0; e < 8; e++){
                int c = cy*32 + j*8 + e;
                ob[e] = (short)f2bf((tile[nx][c]-m)*r*lnw[c] + lnb[c]);
            }
            *(bf16x8*)(F + (size_t)p*768 + cy*32 + j*8) = ob;
        }
    } else {
        // ---- transposeB, lnt-style: 32 points/block, vectorized 16B stores ----
        float (*tile)[257] = (float(*)[257])smem;
        const int nx = tid & 31, cy = tid >> 5;
        const int pbase = (bid - 1122) * 32;
        const int b = pbase >> 12, n0 = pbase & 4095;
        const float* sp = featB + (size_t)b*C_*N_ + n0;
        #pragma unroll 4
        for (int it = 0; it < 32; it++){
            int c = cy + it*8;
            tile[nx][c] = sp[(size_t)c*N_ + nx];
        }
        __syncthreads();
        const int p = pbase + nx;
        #pragma unroll
        for (int j = 0; j < 4; j++){
            bf16x8 ob;
            #pragma unroll
            for (int e = 0; e < 8; e++){
                int c = cy*32 + j*8 + e;
                ob[e] = (short)f2bf(tile[nx][c]);
            }
            *(bf16x8*)(XBT + (size_t)p*256 + cy*32 + j*8) = ob;
        }
    }
}

// ---------------- KNN: 2 queries per wave, float-domain select (round-16) --------
__global__ __launch_bounds__(256) void k_knn(const float* __restrict__ xyzA,
        const f32x4* __restrict__ PB, int* __restrict__ knn){
    const int wv = threadIdx.x >> 6, lane = threadIdx.x & 63;
    const int q0 = blockIdx.x*8 + wv*2;        // 1024 blocks x 4 waves x 2 queries
    const int b = q0 >> 12;
    const f32x4* pb = PB + ((size_t)b << 12);
    const float ax0 = xyzA[(size_t)q0*3],     ay0 = xyzA[(size_t)q0*3+1],     az0 = xyzA[(size_t)q0*3+2];
    const float ax1 = xyzA[(size_t)(q0+1)*3], ay1 = xyzA[(size_t)(q0+1)*3+1], az1 = xyzA[(size_t)(q0+1)*3+2];

    float dm0 = 3.4e38f, dm1 = 3.4e38f;
    int   mi0 = 0, mi1 = 0;
    #pragma unroll 8
    for (int i = 0; i < 64; i++){
        const int m = i*64 + lane;
        f32x4 c = pb[m];
        float d0 = fmaf(ax0, c[0], fmaf(ay0, c[1], fmaf(az0, c[2], c[3])));
        float d1 = fmaf(ax1, c[0], fmaf(ay1, c[1], fmaf(az1, c[2], c[3])));
        if (d0 < dm0){ dm0 = d0; mi0 = m; }
        if (d1 < dm1){ dm1 = d1; mi1 = m; }
    }
    const unsigned long long key0 = (((unsigned long long)mono(dm0)) << 12) | (unsigned int)mi0;
    const unsigned long long key1 = (((unsigned long long)mono(dm1)) << 12) | (unsigned int)mi1;
    unsigned int rk0 = 0, rk1 = 0;
    for (int j = 0; j < 64; j++){
        unsigned long long o0 = __shfl(key0, j, 64);
        unsigned long long o1 = __shfl(key1, j, 64);
        rk0 += (o0 < key0) ? 1u : 0u;
        rk1 += (o1 < key1) ? 1u : 0u;
    }
    unsigned long long sel0 = (rk0 == 31u) ? key0 : ~0ull;
    unsigned long long sel1 = (rk1 == 31u) ? key1 : ~0ull;
    #pragma unroll
    for (int off = 32; off; off >>= 1){
        unsigned long long o0 = __shfl_xor(sel0, off, 64);
        unsigned long long o1 = __shfl_xor(sel1, off, 64);
        sel0 = o0 < sel0 ? o0 : sel0;
        sel1 = o1 < sel1 ? o1 : sel1;
    }
    const float vf0 = unmono((unsigned int)(sel0 >> 12));
    const float vf1 = unmono((unsigned int)(sel1 >> 12));

    __shared__ unsigned long long cand[8][CAPW];   // 16 KB
    __shared__ unsigned int cnt[8];
    const int s0 = wv*2, s1 = wv*2 + 1;
    if (lane == 0){ cnt[s0] = 0u; cnt[s1] = 0u; }
    #pragma unroll 4
    for (int i = 0; i < 64; i++){
        const int m = i*64 + lane;
        f32x4 c = pb[m];
        float d0 = fmaf(ax0, c[0], fmaf(ay0, c[1], fmaf(az0, c[2], c[3])));
        float d1 = fmaf(ax1, c[0], fmaf(ay1, c[1], fmaf(az1, c[2], c[3])));
        if (d0 <= vf0){
            unsigned int slot = atomicAdd(&cnt[s0], 1u);
            if (slot < CAPW)
                cand[s0][slot] = (((unsigned long long)mono(d0)) << 12) | (unsigned int)m;
        }
        if (d1 <= vf1){
            unsigned int slot = atomicAdd(&cnt[s1], 1u);
            if (slot < CAPW)
                cand[s1][slot] = (((unsigned long long)mono(d1)) << 12) | (unsigned int)m;
        }
    }
    {
        const unsigned int C = cnt[s0];
        if (C <= CAPW){
            for (unsigned int i = lane; i < C; i += 64){
                unsigned long long mk = cand[s0][i];
                unsigned int rank = 0;
                for (unsigned int j = 0; j < C; j++) rank += (cand[s0][j] < mk) ? 1u : 0u;
                if (rank < K_) knn[(size_t)q0*K_ + rank] = (int)(mk & 0xFFFull);
            }
        } else {
            unsigned long long last = 0ull;
            for (int it = 0; it < K_; it++){
                unsigned long long cm = ~0ull;
                #pragma unroll 4
                for (int i = 0; i < 64; i++){
                    const int m = i*64 + lane;
                    f32x4 c = pb[m];
                    float d = fmaf(ax0, c[0], fmaf(ay0, c[1], fmaf(az0, c[2], c[3])));
                    unsigned long long key = (((unsigned long long)mono(d)) << 12) | (unsigned int)m;
                    if (key > last && key < cm) cm = key;
                }
                #pragma unroll
                for (int off = 32; off; off >>= 1){
                    unsigned long long o = __shfl_xor(cm, off, 64);
                    cm = o < cm ? o : cm;
                }
                if (lane == 0) knn[(size_t)q0*K_ + it] = (int)(cm & 0xFFFull);
                last = cm;
            }
        }
    }
    {
        const unsigned int C = cnt[s1];
        if (C <= CAPW){
            for (unsigned int i = lane; i < C; i += 64){
                unsigned long long mk = cand[s1][i];
                unsigned int rank = 0;
                for (unsigned int j = 0; j < C; j++) rank += (cand[s1][j] < mk) ? 1u : 0u;
                if (rank < K_) knn[(size_t)(q0+1)*K_ + rank] = (int)(mk & 0xFFFull);
            }
        } else {
            unsigned long long last = 0ull;
            for (int it = 0; it < K_; it++){
                unsigned long long cm = ~0ull;
                #pragma unroll 4
                for (int i = 0; i < 64; i++){
                    const int m = i*64 + lane;
                    f32x4 c = pb[m];
                    float d = fmaf(ax1, c[0], fmaf(ay1, c[1], fmaf(az1, c[2], c[3])));
                    unsigned long long key = (((unsigned long long)mono(d)) << 12) | (unsigned int)m;
                    if (key > last && key < cm) cm = key;
                }
                #pragma unroll
                for (int off = 32; off; off >>= 1){
                    unsigned long long o = __shfl_xor(cm, off, 64);
                    cm = o < cm ? o : cm;
                }
                if (lane == 0) knn[(size_t)(q0+1)*K_ + it] = (int)(cm & 0xFFFull);
                last = cm;
            }
        }
    }
}

// ---------------- MFMA GEMM body: 128x64 tile, BK=32, gload_lds double buffer ----
template<int MODE>
__device__ __forceinline__ void gemm_body(
    const unsigned short* __restrict__ X, int ldx,
    const unsigned short* __restrict__ W, int Kin,
    const float* __restrict__ e0, const float* __restrict__ e1, const float* __restrict__ e2,
    unsigned short* __restrict__ Y, int ldy,
    const float* __restrict__ resid, float* __restrict__ out,
    unsigned short (*As)[128*32], unsigned short (*Bs)[64*32], int bx, int by)
{
    const int tid = threadIdx.x, wid = tid >> 6, lane = tid & 63;
    const int lr = lane & 15, lg = lane >> 4;
    const int m0 = bx*128, n0 = by*64;
    const int lrow = lane >> 2, lcol = (lane & 3)*8;

    const unsigned short* Ag0 = X + (size_t)(m0 + wid*32 + lrow)*ldx + lcol;
    const unsigned short* Ag1 = X + (size_t)(m0 + wid*32 + 16 + lrow)*ldx + lcol;
    const unsigned short* Bg0 = W + (size_t)(n0 + wid*16 + lrow)*Kin + lcol;

    f32x4 acc[2][4] = {};
    const int NT = Kin >> 5;
    int buf = 0;
    gload_lds16(Ag0, &As[0][(wid*32)*32]);
    gload_lds16(Ag1, &As[0][(wid*32+16)*32]);
    gload_lds16(Bg0, &Bs[0][(wid*16)*32]);
    __syncthreads();
    for (int kt = 0; kt < NT; kt++){
        if (kt + 1 < NT){
            const int k = (kt+1)*32;
            gload_lds16(Ag0 + k, &As[buf^1][(wid*32)*32]);
            gload_lds16(Ag1 + k, &As[buf^1][(wid*32+16)*32]);
            gload_lds16(Bg0 + k, &Bs[buf^1][(wid*16)*32]);
        }
        bf16x8 a[2], b[4];
        #pragma unroll
        for (int mi = 0; mi < 2; mi++)
            a[mi] = *(const bf16x8*)&As[buf][(wid*32 + mi*16 + lr)*32 + lg*8];
        #pragma unroll
        for (int ni = 0; ni < 4; ni++)
            b[ni] = *(const bf16x8*)&Bs[buf][(ni*16 + lr)*32 + lg*8];
        #pragma unroll
        for (int mi = 0; mi < 2; mi++){
            #pragma unroll
            for (int ni = 0; ni < 4; ni++)
                acc[mi][ni] = __builtin_amdgcn_mfma_f32_16x16x32_bf16(a[mi], b[ni], acc[mi][ni], 0, 0, 0);
        }
        __syncthreads();
        buf ^= 1;
    }
    #pragma unroll
    for (int mi = 0; mi < 2; mi++){
        const int pbase = m0 + wid*32 + mi*16 + lg*4;
        #pragma unroll
        for (int ni = 0; ni < 4; ni++){
            const int o = n0 + ni*16 + lr;
            if (MODE == 0){
                const float* bp = (o < 256) ? e0 : ((o < 512) ? e1 : e2);
                float bias = bp[o & 255];
                #pragma unroll
                for (int r = 0; r < 4; r++)
                    Y[(size_t)(pbase + r)*ldy + o] = f2bf(acc[mi][ni][r] + bias);
            } else if (MODE == 1){
                float sc = e0[o] * 0.9999950000374997f;
                float sh = e1[o];
                #pragma unroll
                for (int r = 0; r < 4; r++){
                    float vv = fmaf(acc[mi][ni][r], sc, sh);
                    Y[(size_t)(pbase + r)*ldy + o] = f2bf(fmaxf(vv, 0.f));
                }
            } else {
                float bias = e0[o];
                const int b = pbase >> 12, nn = pbase & 4095;
                const size_t adr = ((size_t)b*C_ + o)*N_ + nn;
                f32x4 rv = *(const f32x4*)(resid + adr);
                f32x4 ov;
                #pragma unroll
                for (int r = 0; r < 4; r++) ov[r] = acc[mi][ni][r] + bias + rv[r];
                *(f32x4*)(out + adr) = ov;
            }
        }
    }
}

__global__ __launch_bounds__(256) void k_proj(
    const unsigned short* __restrict__ F, const unsigned short* __restrict__ XBT,
    const unsigned short* __restrict__ WQcat, const unsigned short* __restrict__ WKVD,
    const float* __restrict__ bq, const float* __restrict__ bqd,
    const float* __restrict__ bk, const float* __restrict__ bv, const float* __restrict__ bkd,
    unsigned short* __restrict__ QQ, unsigned short* __restrict__ KVD)
{
    __shared__ __align__(16) unsigned short As[2][128*32];
    __shared__ __align__(16) unsigned short Bs[2][64*32];
    if (blockIdx.y < 8)
        gemm_body<0>(F, 768, WQcat, 256, bq, bqd, nullptr, QQ, 512, nullptr, nullptr,
                     As, Bs, blockIdx.x, blockIdx.y);
    else
        gemm_body<0>(XBT, 256, WKVD, 256, bk, bv, bkd, KVD, 768, nullptr, nullptr,
                     As, Bs, blockIdx.x, blockIdx.y - 8);
}

template<int MODE>
__global__ __launch_bounds__(256) void k_gemm(
    const unsigned short* __restrict__ X, int ldx,
    const unsigned short* __restrict__ W, int Kin,
    const float* __restrict__ e0, const float* __restrict__ e1, const float* __restrict__ e2,
    unsigned short* __restrict__ Y, int ldy,
    const float* __restrict__ resid, float* __restrict__ out)
{
    __shared__ __align__(16) unsigned short As[2][128*32];
    __shared__ __align__(16) unsigned short Bs[2][64*32];
    gemm_body<MODE>(X, ldx, W, Kin, e0, e1, e2, Y, ldy, resid, out,
                    As, Bs, blockIdx.x, blockIdx.y);
}

// ---------------- dual-path neighbor attention: row-cooperative gathers -----------
// (round-16 version, verbatim)
__global__ __launch_bounds__(128) void k_attn(
    const unsigned short* __restrict__ QQ, const unsigned short* __restrict__ KVD,
    const int* __restrict__ KNN, const int* __restrict__ order,
    const float* __restrict__ lnsw, const float* __restrict__ lnsb,
    const float* __restrict__ lndw, const float* __restrict__ lndb,
    unsigned short* __restrict__ F)
{
    __shared__ int   idx_l[2][32];
    __shared__ float part_l[2][4];

    const int tid = threadIdx.x;
    const int wh = tid >> 6, lane = tid & 63;
    const int bid = blockIdx.x;
    const int xcd = bid & 7, ib = bid >> 3;
    const int batch = xcd & 1, quarter = xcd >> 1;
    const int p = order[(batch << 12) + quarter*1024 + ib];
    const int b = batch;

    if (lane < 32) idx_l[wh][lane] = KNN[(size_t)p*K_ + lane];

    const int tq = lane >> 4, c = lane & 15;

    float qsf[8], qdf[8];
    {
        const unsigned short* qrow = QQ + (size_t)p*512 + wh*128 + c*8;
        bf16x8 qs8 = *(const bf16x8*)(qrow);
        bf16x8 qd8 = *(const bf16x8*)(qrow + 256);
        #pragma unroll
        for (int e = 0; e < 8; e++){
            qsf[e] = bf2f((unsigned short)qs8[e]);
            qdf[e] = bf2f((unsigned short)qd8[e]);
        }
    }
    const unsigned short* KB = KVD + (size_t)(b << 12)*768;
    int nbt[8];
    #pragma unroll
    for (int i = 0; i < 8; i++) nbt[i] = idx_l[wh][tq + i*4];

    float s[8];
    {
        bf16x8 kx[8];
        #pragma unroll
        for (int i = 0; i < 8; i++)
            kx[i] = *(const bf16x8*)(KB + (size_t)nbt[i]*768 + wh*128 + c*8);
        #pragma unroll
        for (int i = 0; i < 8; i++){
            float a = 0.f;
            #pragma unroll
            for (int e = 0; e < 8; e++)
                a = fmaf(qsf[e], bf2f((unsigned short)kx[i][e]), a);
            s[i] = a;
        }
    }
    float t[8];
    {
        bf16x8 dx[8];
        #pragma unroll
        for (int i = 0; i < 8; i++)
            dx[i] = *(const bf16x8*)(KB + (size_t)nbt[i]*768 + 512 + wh*128 + c*8);
        #pragma unroll
        for (int i = 0; i < 8; i++){
            float a = 0.f;
            #pragma unroll
            for (int e = 0; e < 8; e++){
                float df = qdf[e] - bf2f((unsigned short)dx[i][e]);
                a = fmaf(df, df, a);
            }
            t[i] = a;
        }
    }
    bf16x8 vx[8];
    #pragma unroll
    for (int i = 0; i < 8; i++)
        vx[i] = *(const bf16x8*)(KB + (size_t)nbt[i]*768 + 256 + wh*128 + c*8);

    #pragma unroll
    for (int i = 0; i < 8; i++){
        s[i] += __shfl_xor(s[i], 1, 64); s[i] += __shfl_xor(s[i], 2, 64);
        t[i] += __shfl_xor(t[i], 1, 64); t[i] += __shfl_xor(t[i], 2, 64);
    }
    float sim[8], dist[8];
    #pragma unroll
    for (int i = 0; i < 8; i++){
        sim[i]  = s[i] * 0.17677669529663687f;   // 1/sqrt(32)
        dist[i] = sqrtf(t[i]);
    }
    float m1 = sim[0], m2 = dist[0];
    #pragma unroll
    for (int i = 1; i < 8; i++){ m1 = fmaxf(m1, sim[i]); m2 = fmaxf(m2, dist[i]); }
    m1 = fmaxf(m1, __shfl_xor(m1, 16, 64)); m1 = fmaxf(m1, __shfl_xor(m1, 32, 64));
    m2 = fmaxf(m2, __shfl_xor(m2, 16, 64)); m2 = fmaxf(m2, __shfl_xor(m2, 32, 64));
    float e1[8], e2[8], s1 = 0.f, s2 = 0.f;
    #pragma unroll
    for (int i = 0; i < 8; i++){
        e1[i] = __expf(sim[i] - m1);  s1 += e1[i];
        e2[i] = __expf(dist[i] - m2); s2 += e2[i];
    }
    s1 += __shfl_xor(s1, 16, 64); s1 += __shfl_xor(s1, 32, 64);
    s2 += __shfl_xor(s2, 16, 64); s2 += __shfl_xor(s2, 32, 64);
    const float r1i = 1.f / s1, r2i = 1.f / s2;

    float cs[8] = {0,0,0,0,0,0,0,0}, cd[8] = {0,0,0,0,0,0,0,0};
    #pragma unroll
    for (int i = 0; i < 8; i++){
        const float w1 = e1[i] * r1i;
        const float w2 = e2[i] * r2i;
        #pragma unroll
        for (int e = 0; e < 8; e++){
            float vf = bf2f((unsigned short)vx[i][e]);
            cs[e] = fmaf(w1, vf, cs[e]);
            cd[e] = fmaf(w2, vf, cd[e]);
        }
    }
    #pragma unroll
    for (int e = 0; e < 8; e++){
        cs[e] += __shfl_xor(cs[e], 16, 64); cs[e] += __shfl_xor(cs[e], 32, 64);
        cd[e] += __shfl_xor(cd[e], 16, 64); cd[e] += __shfl_xor(cd[e], 32, 64);
    }
    float s1n = 0.f, q1n = 0.f, s2n = 0.f, q2n = 0.f;
    #pragma unroll
    for (int e = 0; e < 8; e++){
        s1n += cs[e]; q1n = fmaf(cs[e], cs[e], q1n);
        s2n += cd[e]; q2n = fmaf(cd[e], cd[e], q2n);
    }
    #pragma unroll
    for (int off = 1; off < 16; off <<= 1){
        s1n += __shfl_xor(s1n, off, 64); q1n += __shfl_xor(q1n, off, 64);
        s2n += __shfl_xor(s2n, off, 64); q2n += __shfl_xor(q2n, off, 64);
    }
    if (lane == 0){
        part_l[wh][0] = s1n; part_l[wh][1] = q1n;
        part_l[wh][2] = s2n; part_l[wh][3] = q2n;
    }
    __syncthreads();
    const float S1 = s1n + part_l[wh^1][0];
    const float Q1 = q1n + part_l[wh^1][1];
    const float S2 = s2n + part_l[wh^1][2];
    const float Q2 = q2n + part_l[wh^1][3];
    const float mm1 = S1*(1.f/256.f), mm2 = S2*(1.f/256.f);
    const float rr1 = rsqrtf(Q1*(1.f/256.f) - mm1*mm1 + 1e-5f);
    const float rr2 = rsqrtf(Q2*(1.f/256.f) - mm2*mm2 + 1e-5f);

    if (tq == 0){
        bf16x8 ob;
        #pragma unroll
        for (int e = 0; e < 8; e++){
            const int cg = wh*128 + c*8 + e;
            ob[e] = (short)f2bf((cs[e]-mm1)*rr1*lnsw[cg] + lnsb[cg]);
        }
        *(bf16x8*)(F + (size_t)p*768 + 256 + wh*128 + c*8) = ob;
    } else if (tq == 1){
        bf16x8 ob;
        #pragma unroll
        for (int e = 0; e < 8; e++){
            const int cg = wh*128 + c*8 + e;
            ob[e] = (short)f2bf((cd[e]-mm2)*rr2*lndw[cg] + lndb[cg]);
        }
        *(bf16x8*)(F + (size_t)p*768 + 512 + wh*128 + c*8) = ob;
    }
}

extern "C" void kernel_launch(void* const* d_in, const int* in_sizes, int n_in,
                              void* d_out, int out_size, void* d_ws, size_t ws_size,
                              hipStream_t stream)
{
    const float* xyzA   = (const float*)d_in[0];
    const float* xyzB   = (const float*)d_in[1];
    const float* featA  = (const float*)d_in[2];
    const float* featB  = (const float*)d_in[3];
    const float* ln_in_w= (const float*)d_in[4];
    const float* ln_in_b= (const float*)d_in[5];
    const float* wq  = (const float*)d_in[6];
    const float* bq  = (const float*)d_in[7];
    const float* wk  = (const float*)d_in[8];
    const float* bk  = (const float*)d_in[9];
    const float* wv  = (const float*)d_in[10];
    const float* bv  = (const float*)d_in[11];
    const float* wqd = (const float*)d_in[12];
    const float* bqd = (const float*)d_in[13];
    const float* wkd = (const float*)d_in[14];
    const float* bkd = (const float*)d_in[15];
    const float* lnsw = (const float*)d_in[16];
    const float* lnsb = (const float*)d_in[17];
    const float* lndw = (const float*)d_in[18];
    const float* lndb = (const float*)d_in[19];
    const float* fw1 = (const float*)d_in[20];
    const float* bng = (const float*)d_in[21];
    const float* bnb = (const float*)d_in[22];
    const float* fw2 = (const float*)d_in[23];
    const float* fb2 = (const float*)d_in[24];
    float* out = (float*)d_out;
    char* ws = (char*)d_ws;

    unsigned short* F    = (unsigned short*)(ws + 0);          // 8192*768 bf16
    unsigned short* XBT  = (unsigned short*)(ws + 12582912);   // 8192*256
    unsigned short* QQ   = (unsigned short*)(ws + 16777216);   // 8192*512
    unsigned short* KVD  = (unsigned short*)(ws + 25165824);   // 8192*768
    unsigned short* Y1   = (unsigned short*)(ws + 37748736);   // 8192*512 ; PB earlier
    f32x4*          PB   = (f32x4*)(ws + 37748736);            // dead before fus1
    int*            KNNi = (int*)(ws + 46137344);              // 8192*32
    int*            ORD  = (int*)(ws + 47185920);              // 8192*4
    unsigned short* Wb   = (unsigned short*)(ws + 47251456);   // 851968 bf16
    unsigned short* WQcat = Wb;                // 512x256
    unsigned short* WKVD  = Wb + 131072;       // 768x256
    unsigned short* W1b   = Wb + 327680;       // 512x768
    unsigned short* W2b   = Wb + 720896;       // 256x512

    k_pre<<<1378, 256, 0, stream>>>(wq, wqd, wk, wv, wkd, fw1, fw2, Wb,
                                    xyzB, PB, xyzA, ORD,
                                    featA, ln_in_w, ln_in_b, F, featB, XBT);
    k_knn<<<1024, 256, 0, stream>>>(xyzA, PB, KNNi);

    k_proj<<<dim3(64,20), 256, 0, stream>>>(F, XBT, WQcat, WKVD, bq, bqd, bk, bv, bkd, QQ, KVD);

    k_attn<<<8192, 128, 0, stream>>>(QQ, KVD, KNNi, ORD, lnsw, lnsb, lndw, lndb, F);

    k_gemm<1><<<dim3(64,8), 256, 0, stream>>>(F,  768, W1b, 768, bng, bnb, nullptr, Y1, 512, nullptr, nullptr);
    k_gemm<2><<<dim3(64,4), 256, 0, stream>>>(Y1, 512, W2b, 512, fb2, nullptr, nullptr, nullptr, 0, featA, out);
}

// Round 20
// 125.267 us; speedup vs baseline: 1.1059x; 1.0263x over previous
//
#include <hip/hip_runtime.h>
#include <hip/hip_bf16.h>
#include <math.h>

#define B_ 2
#define N_ 4096
#define C_ 256
#define H_ 8
#define K_ 32
#define NP_ (B_*N_)
#define CAPW 256

typedef __attribute__((ext_vector_type(8))) short bf16x8;
typedef __attribute__((ext_vector_type(4))) float f32x4;
typedef __attribute__((ext_vector_type(4))) unsigned short ushort4_t;

#define DOT2BF(acc, a, b) asm("v_dot2_f32_bf16 %0, %1, %2, %0" : "+v"(acc) : "v"(a), "v"(b))

__device__ __forceinline__ float bf2f(unsigned short v){
    union { unsigned int u; float f; } x; x.u = ((unsigned int)v) << 16; return x.f;
}
__device__ __forceinline__ unsigned short f2bf(float f){
    union { float f; unsigned int u; } x; x.f = f;
    return (unsigned short)((x.u + 0x7FFFu + ((x.u >> 16) & 1u)) >> 16);
}
__device__ __forceinline__ unsigned int mono(float f){
    union { float f; unsigned int u; } x; x.f = f;
    return x.u ^ (0x80000000u | (unsigned int)((int)x.u >> 31));
}
__device__ __forceinline__ float unmono(unsigned int u){
    union { unsigned int u; float f; } x;
    x.u = (u & 0x80000000u) ? (u ^ 0x80000000u) : ~u;
    return x.f;
}
__device__ __forceinline__ void gload_lds16(const unsigned short* g, unsigned short* l){
    __builtin_amdgcn_global_load_lds(
        (const __attribute__((address_space(1))) unsigned int*)g,
        (__attribute__((address_space(3))) unsigned int*)l, 16, 0, 0);
}

// ================= mega-prologue: cvt | prep | morton | lnt | transposeB =========
__global__ __launch_bounds__(256) void k_pre(
    const float* __restrict__ s0, const float* __restrict__ s1,
    const float* __restrict__ s2, const float* __restrict__ s3,
    const float* __restrict__ s4, const float* __restrict__ s5,
    const float* __restrict__ s6, unsigned short* __restrict__ Wb,
    const float* __restrict__ xyzB, f32x4* __restrict__ PB,
    const float* __restrict__ xyzA, int* __restrict__ order,
    const float* __restrict__ featA, const float* __restrict__ lnw,
    const float* __restrict__ lnb, unsigned short* __restrict__ F,
    const float* __restrict__ featB, unsigned short* __restrict__ XBT)
{
    __shared__ __align__(16) char smem[35200];
    const int bid = blockIdx.x;
    const int tid = threadIdx.x;
    if (bid < 832){
        int i = (bid*256 + tid)*4;
        const float* s; int off;
        if (i < 327680){
            int seg = i >> 16;
            s = (seg==0)?s0:(seg==1)?s1:(seg==2)?s2:(seg==3)?s3:s4;
            off = i & 65535;
        } else if (i < 720896){
            s = s5; off = i - 327680;
        } else {
            s = s6; off = i - 720896;
        }
        f32x4 v = *(const f32x4*)(s + off);
        ushort4_t o;
        #pragma unroll
        for (int e = 0; e < 4; e++) o[e] = f2bf(v[e]);
        *(ushort4_t*)(Wb + i) = o;
    } else if (bid < 864){
        int i = (bid - 832)*256 + tid;
        float x = xyzB[i*3], y = xyzB[i*3+1], z = xyzB[i*3+2];
        f32x4 o;
        o[0] = -2.f*x; o[1] = -2.f*y; o[2] = -2.f*z;
        o[3] = x*x + y*y + z*z;
        PB[i] = o;
    } else if (bid < 866){
        unsigned int* hist = (unsigned int*)smem;
        unsigned int* wsum = (unsigned int*)(smem + 4096);
        const int b = bid - 864;
        const int wv = tid >> 6, lane = tid & 63;
        for (int i = tid; i < 1024; i += 256) hist[i] = 0u;
        __syncthreads();
        unsigned int code[16];
        #pragma unroll
        for (int i = 0; i < 16; i++){
            const int n = tid + i*256;
            const float* pp = xyzA + (size_t)((b<<12) + n)*3;
            int qx = (int)fminf(fmaxf((pp[0] + 5.f)*1.6f, 0.f), 15.f);
            int qy = (int)fminf(fmaxf((pp[1] + 5.f)*0.8f, 0.f), 7.f);
            int qz = (int)fminf(fmaxf((pp[2] + 5.f)*0.8f, 0.f), 7.f);
            unsigned int c = (unsigned int)((qx & 1) | ((qz & 1) << 1) | ((qy & 1) << 2)
                           | (((qx >> 1) & 1) << 3) | (((qz >> 1) & 1) << 4) | (((qy >> 1) & 1) << 5)
                           | (((qx >> 2) & 1) << 6) | (((qz >> 2) & 1) << 7) | (((qy >> 2) & 1) << 8)
                           | (((qx >> 3) & 1) << 9));
            code[i] = c;
            atomicAdd(&hist[c], 1u);
        }
        __syncthreads();
        unsigned int loc[4], t4 = 0;
        #pragma unroll
        for (int j = 0; j < 4; j++){ loc[j] = hist[tid*4 + j]; t4 += loc[j]; }
        unsigned int sc = t4;
        #pragma unroll
        for (int off = 1; off < 64; off <<= 1){
            unsigned int o = __shfl_up(sc, off, 64);
            if (lane >= off) sc += o;
        }
        if (lane == 63) wsum[wv] = sc;
        __syncthreads();
        unsigned int wb = 0;
        #pragma unroll
        for (int j = 0; j < 4; j++) if (j < wv) wb += wsum[j];
        unsigned int base = wb + sc - t4;
        #pragma unroll
        for (int j = 0; j < 4; j++){ hist[tid*4 + j] = base; base += loc[j]; }
        __syncthreads();
        #pragma unroll
        for (int i = 0; i < 16; i++){
            const int n = tid + i*256;
            unsigned int pos = atomicAdd(&hist[code[i]], 1u);
            order[(b<<12) + pos] = (b<<12) | n;
        }
    } else if (bid < 1122){
        float (*tile)[257] = (float(*)[257])smem;
        float (*ps)[32]    = (float(*)[32])(smem + 32896);
        float (*pq)[32]    = (float(*)[32])(smem + 33920);
        float (*st)[32]    = (float(*)[32])(smem + 34944);
        const int nx = tid & 31, cy = tid >> 5;
        const int pbase = (bid - 866) * 32;
        const int b = pbase >> 12, n0 = pbase & 4095;
        const float* sp = featA + (size_t)b*C_*N_ + n0;
        #pragma unroll 4
        for (int it = 0; it < 32; it++){
            int c = cy + it*8;
            tile[nx][c] = sp[(size_t)c*N_ + nx];
        }
        __syncthreads();
        {
            float s = 0.f, q = 0.f;
            #pragma unroll 8
            for (int i = 0; i < 32; i++){
                int cc = cy*32 + ((i + cy) & 31);
                float x = tile[nx][cc];
                s += x; q = fmaf(x, x, q);
            }
            ps[cy][nx] = s; pq[cy][nx] = q;
        }
        __syncthreads();
        if (tid < 32){
            float S = 0.f, Q = 0.f;
            #pragma unroll
            for (int j = 0; j < 8; j++){ S += ps[j][tid]; Q += pq[j][tid]; }
            float m = S*(1.f/256.f);
            float v = Q*(1.f/256.f) - m*m;
            st[0][tid] = m; st[1][tid] = rsqrtf(v + 1e-5f);
        }
        __syncthreads();
        const int p = pbase + nx;
        const float m = st[0][nx], r = st[1][nx];
        #pragma unroll
        for (int j = 0; j < 4; j++){
            bf16x8 ob;
            #pragma unroll
            for (int e = 0; e < 8; e++){
                int c = cy*32 + j*8 + e;
                ob[e] = (short)f2bf((tile[nx][c]-m)*r*lnw[c] + lnb[c]);
            }
            *(bf16x8*)(F + (size_t)p*768 + cy*32 + j*8) = ob;
        }
    } else {
        float (*tile)[257] = (float(*)[257])smem;
        const int nx = tid & 31, cy = tid >> 5;
        const int pbase = (bid - 1122) * 32;
        const int b = pbase >> 12, n0 = pbase & 4095;
        const float* sp = featB + (size_t)b*C_*N_ + n0;
        #pragma unroll 4
        for (int it = 0; it < 32; it++){
            int c = cy + it*8;
            tile[nx][c] = sp[(size_t)c*N_ + nx];
        }
        __syncthreads();
        const int p = pbase + nx;
        #pragma unroll
        for (int j = 0; j < 4; j++){
            bf16x8 ob;
            #pragma unroll
            for (int e = 0; e < 8; e++){
                int c = cy*32 + j*8 + e;
                ob[e] = (short)f2bf(tile[nx][c]);
            }
            *(bf16x8*)(XBT + (size_t)p*256 + cy*32 + j*8) = ob;
        }
    }
}

// ---------------- KNN: 2 queries per wave, float-domain select ----------------
__global__ __launch_bounds__(256) void k_knn(const float* __restrict__ xyzA,
        const f32x4* __restrict__ PB, int* __restrict__ knn){
    const int wv = threadIdx.x >> 6, lane = threadIdx.x & 63;
    const int q0 = blockIdx.x*8 + wv*2;
    const int b = q0 >> 12;
    const f32x4* pb = PB + ((size_t)b << 12);
    const float ax0 = xyzA[(size_t)q0*3],     ay0 = xyzA[(size_t)q0*3+1],     az0 = xyzA[(size_t)q0*3+2];
    const float ax1 = xyzA[(size_t)(q0+1)*3], ay1 = xyzA[(size_t)(q0+1)*3+1], az1 = xyzA[(size_t)(q0+1)*3+2];

    float dm0 = 3.4e38f, dm1 = 3.4e38f;
    int   mi0 = 0, mi1 = 0;
    #pragma unroll 8
    for (int i = 0; i < 64; i++){
        const int m = i*64 + lane;
        f32x4 c = pb[m];
        float d0 = fmaf(ax0, c[0], fmaf(ay0, c[1], fmaf(az0, c[2], c[3])));
        float d1 = fmaf(ax1, c[0], fmaf(ay1, c[1], fmaf(az1, c[2], c[3])));
        if (d0 < dm0){ dm0 = d0; mi0 = m; }
        if (d1 < dm1){ dm1 = d1; mi1 = m; }
    }
    const unsigned long long key0 = (((unsigned long long)mono(dm0)) << 12) | (unsigned int)mi0;
    const unsigned long long key1 = (((unsigned long long)mono(dm1)) << 12) | (unsigned int)mi1;
    unsigned int rk0 = 0, rk1 = 0;
    for (int j = 0; j < 64; j++){
        unsigned long long o0 = __shfl(key0, j, 64);
        unsigned long long o1 = __shfl(key1, j, 64);
        rk0 += (o0 < key0) ? 1u : 0u;
        rk1 += (o1 < key1) ? 1u : 0u;
    }
    unsigned long long sel0 = (rk0 == 31u) ? key0 : ~0ull;
    unsigned long long sel1 = (rk1 == 31u) ? key1 : ~0ull;
    #pragma unroll
    for (int off = 32; off; off >>= 1){
        unsigned long long o0 = __shfl_xor(sel0, off, 64);
        unsigned long long o1 = __shfl_xor(sel1, off, 64);
        sel0 = o0 < sel0 ? o0 : sel0;
        sel1 = o1 < sel1 ? o1 : sel1;
    }
    const float vf0 = unmono((unsigned int)(sel0 >> 12));
    const float vf1 = unmono((unsigned int)(sel1 >> 12));

    __shared__ unsigned long long cand[8][CAPW];
    __shared__ unsigned int cnt[8];
    const int s0 = wv*2, s1 = wv*2 + 1;
    if (lane == 0){ cnt[s0] = 0u; cnt[s1] = 0u; }
    #pragma unroll 4
    for (int i = 0; i < 64; i++){
        const int m = i*64 + lane;
        f32x4 c = pb[m];
        float d0 = fmaf(ax0, c[0], fmaf(ay0, c[1], fmaf(az0, c[2], c[3])));
        float d1 = fmaf(ax1, c[0], fmaf(ay1, c[1], fmaf(az1, c[2], c[3])));
        if (d0 <= vf0){
            unsigned int slot = atomicAdd(&cnt[s0], 1u);
            if (slot < CAPW)
                cand[s0][slot] = (((unsigned long long)mono(d0)) << 12) | (unsigned int)m;
        }
        if (d1 <= vf1){
            unsigned int slot = atomicAdd(&cnt[s1], 1u);
            if (slot < CAPW)
                cand[s1][slot] = (((unsigned long long)mono(d1)) << 12) | (unsigned int)m;
        }
    }
    {
        const unsigned int C = cnt[s0];
        if (C <= CAPW){
            for (unsigned int i = lane; i < C; i += 64){
                unsigned long long mk = cand[s0][i];
                unsigned int rank = 0;
                for (unsigned int j = 0; j < C; j++) rank += (cand[s0][j] < mk) ? 1u : 0u;
                if (rank < K_) knn[(size_t)q0*K_ + rank] = (int)(mk & 0xFFFull);
            }
        } else {
            unsigned long long last = 0ull;
            for (int it = 0; it < K_; it++){
                unsigned long long cm = ~0ull;
                #pragma unroll 4
                for (int i = 0; i < 64; i++){
                    const int m = i*64 + lane;
                    f32x4 c = pb[m];
                    float d = fmaf(ax0, c[0], fmaf(ay0, c[1], fmaf(az0, c[2], c[3])));
                    unsigned long long key = (((unsigned long long)mono(d)) << 12) | (unsigned int)m;
                    if (key > last && key < cm) cm = key;
                }
                #pragma unroll
                for (int off = 32; off; off >>= 1){
                    unsigned long long o = __shfl_xor(cm, off, 64);
                    cm = o < cm ? o : cm;
                }
                if (lane == 0) knn[(size_t)q0*K_ + it] = (int)(cm & 0xFFFull);
                last = cm;
            }
        }
    }
    {
        const unsigned int C = cnt[s1];
        if (C <= CAPW){
            for (unsigned int i = lane; i < C; i += 64){
                unsigned long long mk = cand[s1][i];
                unsigned int rank = 0;
                for (unsigned int j = 0; j < C; j++) rank += (cand[s1][j] < mk) ? 1u : 0u;
                if (rank < K_) knn[(size_t)(q0+1)*K_ + rank] = (int)(mk & 0xFFFull);
            }
        } else {
            unsigned long long last = 0ull;
            for (int it = 0; it < K_; it++){
                unsigned long long cm = ~0ull;
                #pragma unroll 4
                for (int i = 0; i < 64; i++){
                    const int m = i*64 + lane;
                    f32x4 c = pb[m];
                    float d = fmaf(ax1, c[0], fmaf(ay1, c[1], fmaf(az1, c[2], c[3])));
                    unsigned long long key = (((unsigned long long)mono(d)) << 12) | (unsigned int)m;
                    if (key > last && key < cm) cm = key;
                }
                #pragma unroll
                for (int off = 32; off; off >>= 1){
                    unsigned long long o = __shfl_xor(cm, off, 64);
                    cm = o < cm ? o : cm;
                }
                if (lane == 0) knn[(size_t)(q0+1)*K_ + it] = (int)(cm & 0xFFFull);
                last = cm;
            }
        }
    }
}

// ---------------- MFMA GEMM body: 128x64 tile, BK=32, gload_lds double buffer ----
template<int MODE>
__device__ __forceinline__ void gemm_body(
    const unsigned short* __restrict__ X, int ldx,
    const unsigned short* __restrict__ W, int Kin,
    const float* __restrict__ e0, const float* __restrict__ e1, const float* __restrict__ e2,
    unsigned short* __restrict__ Y, int ldy,
    const float* __restrict__ resid, float* __restrict__ out,
    unsigned short (*As)[128*32], unsigned short (*Bs)[64*32], int bx, int by)
{
    const int tid = threadIdx.x, wid = tid >> 6, lane = tid & 63;
    const int lr = lane & 15, lg = lane >> 4;
    const int m0 = bx*128, n0 = by*64;
    const int lrow = lane >> 2, lcol = (lane & 3)*8;

    const unsigned short* Ag0 = X + (size_t)(m0 + wid*32 + lrow)*ldx + lcol;
    const unsigned short* Ag1 = X + (size_t)(m0 + wid*32 + 16 + lrow)*ldx + lcol;
    const unsigned short* Bg0 = W + (size_t)(n0 + wid*16 + lrow)*Kin + lcol;

    f32x4 acc[2][4] = {};
    const int NT = Kin >> 5;
    int buf = 0;
    gload_lds16(Ag0, &As[0][(wid*32)*32]);
    gload_lds16(Ag1, &As[0][(wid*32+16)*32]);
    gload_lds16(Bg0, &Bs[0][(wid*16)*32]);
    __syncthreads();
    for (int kt = 0; kt < NT; kt++){
        if (kt + 1 < NT){
            const int k = (kt+1)*32;
            gload_lds16(Ag0 + k, &As[buf^1][(wid*32)*32]);
            gload_lds16(Ag1 + k, &As[buf^1][(wid*32+16)*32]);
            gload_lds16(Bg0 + k, &Bs[buf^1][(wid*16)*32]);
        }
        bf16x8 a[2], b[4];
        #pragma unroll
        for (int mi = 0; mi < 2; mi++)
            a[mi] = *(const bf16x8*)&As[buf][(wid*32 + mi*16 + lr)*32 + lg*8];
        #pragma unroll
        for (int ni = 0; ni < 4; ni++)
            b[ni] = *(const bf16x8*)&Bs[buf][(ni*16 + lr)*32 + lg*8];
        #pragma unroll
        for (int mi = 0; mi < 2; mi++){
            #pragma unroll
            for (int ni = 0; ni < 4; ni++)
                acc[mi][ni] = __builtin_amdgcn_mfma_f32_16x16x32_bf16(a[mi], b[ni], acc[mi][ni], 0, 0, 0);
        }
        __syncthreads();
        buf ^= 1;
    }
    #pragma unroll
    for (int mi = 0; mi < 2; mi++){
        const int pbase = m0 + wid*32 + mi*16 + lg*4;
        #pragma unroll
        for (int ni = 0; ni < 4; ni++){
            const int o = n0 + ni*16 + lr;
            if (MODE == 0){
                const float* bp = (o < 256) ? e0 : ((o < 512) ? e1 : e2);
                float bias = bp[o & 255];
                #pragma unroll
                for (int r = 0; r < 4; r++)
                    Y[(size_t)(pbase + r)*ldy + o] = f2bf(acc[mi][ni][r] + bias);
            } else if (MODE == 1){
                float sc = e0[o] * 0.9999950000374997f;
                float sh = e1[o];
                #pragma unroll
                for (int r = 0; r < 4; r++){
                    float vv = fmaf(acc[mi][ni][r], sc, sh);
                    Y[(size_t)(pbase + r)*ldy + o] = f2bf(fmaxf(vv, 0.f));
                }
            } else {
                float bias = e0[o];
                const int b = pbase >> 12, nn = pbase & 4095;
                const size_t adr = ((size_t)b*C_ + o)*N_ + nn;
                f32x4 rv = *(const f32x4*)(resid + adr);
                f32x4 ov;
                #pragma unroll
                for (int r = 0; r < 4; r++) ov[r] = acc[mi][ni][r] + bias + rv[r];
                *(f32x4*)(out + adr) = ov;
            }
        }
    }
}

__global__ __launch_bounds__(256) void k_proj(
    const unsigned short* __restrict__ F, const unsigned short* __restrict__ XBT,
    const unsigned short* __restrict__ WQcat, const unsigned short* __restrict__ WKVD,
    const float* __restrict__ bq, const float* __restrict__ bqd,
    const float* __restrict__ bk, const float* __restrict__ bv, const float* __restrict__ bkd,
    unsigned short* __restrict__ QQ, unsigned short* __restrict__ KVD)
{
    __shared__ __align__(16) unsigned short As[2][128*32];
    __shared__ __align__(16) unsigned short Bs[2][64*32];
    if (blockIdx.y < 8)
        gemm_body<0>(F, 768, WQcat, 256, bq, bqd, nullptr, QQ, 512, nullptr, nullptr,
                     As, Bs, blockIdx.x, blockIdx.y);
    else
        gemm_body<0>(XBT, 256, WKVD, 256, bk, bv, bkd, KVD, 768, nullptr, nullptr,
                     As, Bs, blockIdx.x, blockIdx.y - 8);
}

template<int MODE>
__global__ __launch_bounds__(256) void k_gemm(
    const unsigned short* __restrict__ X, int ldx,
    const unsigned short* __restrict__ W, int Kin,
    const float* __restrict__ e0, const float* __restrict__ e1, const float* __restrict__ e2,
    unsigned short* __restrict__ Y, int ldy,
    const float* __restrict__ resid, float* __restrict__ out)
{
    __shared__ __align__(16) unsigned short As[2][128*32];
    __shared__ __align__(16) unsigned short Bs[2][64*32];
    gemm_body<MODE>(X, ldx, W, Kin, e0, e1, e2, Y, ldy, resid, out,
                    As, Bs, blockIdx.x, blockIdx.y);
}

// ---------------- dual-path neighbor attention: row-cooperative, dot2 sim only ----
__global__ __launch_bounds__(128) void k_attn(
    const unsigned short* __restrict__ QQ, const unsigned short* __restrict__ KVD,
    const int* __restrict__ KNN, const int* __restrict__ order,
    const float* __restrict__ lnsw, const float* __restrict__ lnsb,
    const float* __restrict__ lndw, const float* __restrict__ lndb,
    unsigned short* __restrict__ F)
{
    __shared__ int   idx_l[2][32];
    __shared__ float part_l[2][4];

    const int tid = threadIdx.x;
    const int wh = tid >> 6, lane = tid & 63;
    const int bid = blockIdx.x;
    const int xcd = bid & 7, ib = bid >> 3;
    const int batch = xcd & 1, quarter = xcd >> 1;
    const int p = order[(batch << 12) + quarter*1024 + ib];
    const int b = batch;

    if (lane < 32) idx_l[wh][lane] = KNN[(size_t)p*K_ + lane];

    const int tq = lane >> 4, c = lane & 15;

    // q_s kept packed (for dot2); q_d unpacked (direct-diff dist, known good)
    uint4 qsu;
    float qdf[8];
    {
        const unsigned short* qrow = QQ + (size_t)p*512 + wh*128 + c*8;
        qsu = *(const uint4*)(qrow);
        bf16x8 qd8 = *(const bf16x8*)(qrow + 256);
        #pragma unroll
        for (int e = 0; e < 8; e++) qdf[e] = bf2f((unsigned short)qd8[e]);
    }
    const unsigned short* KB = KVD + (size_t)(b << 12)*768;
    int nbt[8];
    #pragma unroll
    for (int i = 0; i < 8; i++) nbt[i] = idx_l[wh][tq + i*4];

    // QK sim via dot2 (validated round 13)
    float s[8];
    {
        uint4 kx[8];
        #pragma unroll
        for (int i = 0; i < 8; i++)
            kx[i] = *(const uint4*)(KB + (size_t)nbt[i]*768 + wh*128 + c*8);
        #pragma unroll
        for (int i = 0; i < 8; i++){
            float a = 0.f;
            DOT2BF(a, qsu.x, kx[i].x); DOT2BF(a, qsu.y, kx[i].y);
            DOT2BF(a, qsu.z, kx[i].z); DOT2BF(a, qsu.w, kx[i].w);
            s[i] = a;
        }
    }
    // dist via direct diff (known good)
    float t[8];
    {
        bf16x8 dx[8];
        #pragma unroll
        for (int i = 0; i < 8; i++)
            dx[i] = *(const bf16x8*)(KB + (size_t)nbt[i]*768 + 512 + wh*128 + c*8);
        #pragma unroll
        for (int i = 0; i < 8; i++){
            float a = 0.f;
            #pragma unroll
            for (int e = 0; e < 8; e++){
                float df = qdf[e] - bf2f((unsigned short)dx[i][e]);
                a = fmaf(df, df, a);
            }
            t[i] = a;
        }
    }
    bf16x8 vx[8];
    #pragma unroll
    for (int i = 0; i < 8; i++)
        vx[i] = *(const bf16x8*)(KB + (size_t)nbt[i]*768 + 256 + wh*128 + c*8);

    #pragma unroll
    for (int i = 0; i < 8; i++){
        s[i] += __shfl_xor(s[i], 1, 64); s[i] += __shfl_xor(s[i], 2, 64);
        t[i] += __shfl_xor(t[i], 1, 64); t[i] += __shfl_xor(t[i], 2, 64);
    }
    float sim[8], dist[8];
    #pragma unroll
    for (int i = 0; i < 8; i++){
        sim[i]  = s[i] * 0.17677669529663687f;   // 1/sqrt(32)
        dist[i] = sqrtf(t[i]);
    }
    float m1 = sim[0], m2 = dist[0];
    #pragma unroll
    for (int i = 1; i < 8; i++){ m1 = fmaxf(m1, sim[i]); m2 = fmaxf(m2, dist[i]); }
    m1 = fmaxf(m1, __shfl_xor(m1, 16, 64)); m1 = fmaxf(m1, __shfl_xor(m1, 32, 64));
    m2 = fmaxf(m2, __shfl_xor(m2, 16, 64)); m2 = fmaxf(m2, __shfl_xor(m2, 32, 64));
    float e1[8], e2[8], s1 = 0.f, s2 = 0.f;
    #pragma unroll
    for (int i = 0; i < 8; i++){
        e1[i] = __expf(sim[i] - m1);  s1 += e1[i];
        e2[i] = __expf(dist[i] - m2); s2 += e2[i];
    }
    s1 += __shfl_xor(s1, 16, 64); s1 += __shfl_xor(s1, 32, 64);
    s2 += __shfl_xor(s2, 16, 64); s2 += __shfl_xor(s2, 32, 64);
    const float r1i = 1.f / s1, r2i = 1.f / s2;

    float cs[8] = {0,0,0,0,0,0,0,0}, cd[8] = {0,0,0,0,0,0,0,0};
    #pragma unroll
    for (int i = 0; i < 8; i++){
        const float w1 = e1[i] * r1i;
        const float w2 = e2[i] * r2i;
        #pragma unroll
        for (int e = 0; e < 8; e++){
            float vf = bf2f((unsigned short)vx[i][e]);
            cs[e] = fmaf(w1, vf, cs[e]);
            cd[e] = fmaf(w2, vf, cd[e]);
        }
    }
    #pragma unroll
    for (int e = 0; e < 8; e++){
        cs[e] += __shfl_xor(cs[e], 16, 64); cs[e] += __shfl_xor(cs[e], 32, 64);
        cd[e] += __shfl_xor(cd[e], 16, 64); cd[e] += __shfl_xor(cd[e], 32, 64);
    }
    float s1n = 0.f, q1n = 0.f, s2n = 0.f, q2n = 0.f;
    #pragma unroll
    for (int e = 0; e < 8; e++){
        s1n += cs[e]; q1n = fmaf(cs[e], cs[e], q1n);
        s2n += cd[e]; q2n = fmaf(cd[e], cd[e], q2n);
    }
    #pragma unroll
    for (int off = 1; off < 16; off <<= 1){
        s1n += __shfl_xor(s1n, off, 64); q1n += __shfl_xor(q1n, off, 64);
        s2n += __shfl_xor(s2n, off, 64); q2n += __shfl_xor(q2n, off, 64);
    }
    if (lane == 0){
        part_l[wh][0] = s1n; part_l[wh][1] = q1n;
        part_l[wh][2] = s2n; part_l[wh][3] = q2n;
    }
    __syncthreads();
    const float S1 = s1n + part_l[wh^1][0];
    const float Q1 = q1n + part_l[wh^1][1];
    const float S2 = s2n + part_l[wh^1][2];
    const float Q2 = q2n + part_l[wh^1][3];
    const float mm1 = S1*(1.f/256.f), mm2 = S2*(1.f/256.f);
    const float rr1 = rsqrtf(Q1*(1.f/256.f) - mm1*mm1 + 1e-5f);
    const float rr2 = rsqrtf(Q2*(1.f/256.f) - mm2*mm2 + 1e-5f);

    if (tq == 0){
        bf16x8 ob;
        #pragma unroll
        for (int e = 0; e < 8; e++){
            const int cg = wh*128 + c*8 + e;
            ob[e] = (short)f2bf((cs[e]-mm1)*rr1*lnsw[cg] + lnsb[cg]);
        }
        *(bf16x8*)(F + (size_t)p*768 + 256 + wh*128 + c*8) = ob;
    } else if (tq == 1){
        bf16x8 ob;
        #pragma unroll
        for (int e = 0; e < 8; e++){
            const int cg = wh*128 + c*8 + e;
            ob[e] = (short)f2bf((cd[e]-mm2)*rr2*lndw[cg] + lndb[cg]);
        }
        *(bf16x8*)(F + (size_t)p*768 + 512 + wh*128 + c*8) = ob;
    }
}

extern "C" void kernel_launch(void* const* d_in, const int* in_sizes, int n_in,
                              void* d_out, int out_size, void* d_ws, size_t ws_size,
                              hipStream_t stream)
{
    const float* xyzA   = (const float*)d_in[0];
    const float* xyzB   = (const float*)d_in[1];
    const float* featA  = (const float*)d_in[2];
    const float* featB  = (const float*)d_in[3];
    const float* ln_in_w= (const float*)d_in[4];
    const float* ln_in_b= (const float*)d_in[5];
    const float* wq  = (const float*)d_in[6];
    const float* bq  = (const float*)d_in[7];
    const float* wk  = (const float*)d_in[8];
    const float* bk  = (const float*)d_in[9];
    const float* wv  = (const float*)d_in[10];
    const float* bv  = (const float*)d_in[11];
    const float* wqd = (const float*)d_in[12];
    const float* bqd = (const float*)d_in[13];
    const float* wkd = (const float*)d_in[14];
    const float* bkd = (const float*)d_in[15];
    const float* lnsw = (const float*)d_in[16];
    const float* lnsb = (const float*)d_in[17];
    const float* lndw = (const float*)d_in[18];
    const float* lndb = (const float*)d_in[19];
    const float* fw1 = (const float*)d_in[20];
    const float* bng = (const float*)d_in[21];
    const float* bnb = (const float*)d_in[22];
    const float* fw2 = (const float*)d_in[23];
    const float* fb2 = (const float*)d_in[24];
    float* out = (float*)d_out;
    char* ws = (char*)d_ws;

    unsigned short* F    = (unsigned short*)(ws + 0);          // 8192*768 bf16
    unsigned short* XBT  = (unsigned short*)(ws + 12582912);   // 8192*256
    unsigned short* QQ   = (unsigned short*)(ws + 16777216);   // 8192*512
    unsigned short* KVD  = (unsigned short*)(ws + 25165824);   // 8192*768
    unsigned short* Y1   = (unsigned short*)(ws + 37748736);   // 8192*512 ; PB earlier
    f32x4*          PB   = (f32x4*)(ws + 37748736);            // dead before fus1
    int*            KNNi = (int*)(ws + 46137344);              // 8192*32
    int*            ORD  = (int*)(ws + 47185920);              // 8192*4
    unsigned short* Wb   = (unsigned short*)(ws + 47251456);   // 851968 bf16
    unsigned short* WQcat = Wb;                // 512x256
    unsigned short* WKVD  = Wb + 131072;       // 768x256
    unsigned short* W1b   = Wb + 327680;       // 512x768
    unsigned short* W2b   = Wb + 720896;       // 256x512

    k_pre<<<1378, 256, 0, stream>>>(wq, wqd, wk, wv, wkd, fw1, fw2, Wb,
                                    xyzB, PB, xyzA, ORD,
                                    featA, ln_in_w, ln_in_b, F, featB, XBT);
    k_knn<<<1024, 256, 0, stream>>>(xyzA, PB, KNNi);

    k_proj<<<dim3(64,20), 256, 0, stream>>>(F, XBT, WQcat, WKVD, bq, bqd, bk, bv, bkd, QQ, KVD);

    k_attn<<<8192, 128, 0, stream>>>(QQ, KVD, KNNi, ORD, lnsw, lnsb, lndw, lndb, F);

    k_gemm<1><<<dim3(64,8), 256, 0, stream>>>(F,  768, W1b, 768, bng, bnb, nullptr, Y1, 512, nullptr, nullptr);
    k_gemm<2><<<dim3(64,4), 256, 0, stream>>>(Y1, 512, W2b, 512, fb2, nullptr, nullptr, nullptr, 0, featA, out);
}

// Round 21
// 119.868 us; speedup vs baseline: 1.1557x; 1.0450x over previous
//
#include <hip/hip_runtime.h>
#include <hip/hip_bf16.h>
#include <math.h>

#define B_ 2
#define N_ 4096
#define C_ 256
#define H_ 8
#define K_ 32
#define NP_ (B_*N_)
#define CAPW 256

typedef __attribute__((ext_vector_type(8))) short bf16x8;
typedef __attribute__((ext_vector_type(4))) float f32x4;
typedef __attribute__((ext_vector_type(4))) unsigned short ushort4_t;

#define DOT2BF(acc, a, b) asm("v_dot2_f32_bf16 %0, %1, %2, %0" : "+v"(acc) : "v"(a), "v"(b))

__device__ __forceinline__ float bf2f(unsigned short v){
    union { unsigned int u; float f; } x; x.u = ((unsigned int)v) << 16; return x.f;
}
__device__ __forceinline__ unsigned short f2bf(float f){
    union { float f; unsigned int u; } x; x.f = f;
    return (unsigned short)((x.u + 0x7FFFu + ((x.u >> 16) & 1u)) >> 16);
}
__device__ __forceinline__ unsigned int mono(float f){
    union { float f; unsigned int u; } x; x.f = f;
    return x.u ^ (0x80000000u | (unsigned int)((int)x.u >> 31));
}
__device__ __forceinline__ float unmono(unsigned int u){
    union { unsigned int u; float f; } x;
    x.u = (u & 0x80000000u) ? (u ^ 0x80000000u) : ~u;
    return x.f;
}
__device__ __forceinline__ void gload_lds16(const unsigned short* g, unsigned short* l){
    __builtin_amdgcn_global_load_lds(
        (const __attribute__((address_space(1))) unsigned int*)g,
        (__attribute__((address_space(3))) unsigned int*)l, 16, 0, 0);
}

// ================= mega-prologue: cvt | prep | morton | lnt | transposeB =========
__global__ __launch_bounds__(256) void k_pre(
    const float* __restrict__ s0, const float* __restrict__ s1,
    const float* __restrict__ s2, const float* __restrict__ s3,
    const float* __restrict__ s4, const float* __restrict__ s5,
    const float* __restrict__ s6, unsigned short* __restrict__ Wb,
    const float* __restrict__ xyzB, f32x4* __restrict__ PB,
    const float* __restrict__ xyzA, int* __restrict__ order,
    const float* __restrict__ featA, const float* __restrict__ lnw,
    const float* __restrict__ lnb, unsigned short* __restrict__ F,
    const float* __restrict__ featB, unsigned short* __restrict__ XBT)
{
    __shared__ __align__(16) char smem[35200];
    const int bid = blockIdx.x;
    const int tid = threadIdx.x;
    if (bid < 832){
        int i = (bid*256 + tid)*4;
        const float* s; int off;
        if (i < 327680){
            int seg = i >> 16;
            s = (seg==0)?s0:(seg==1)?s1:(seg==2)?s2:(seg==3)?s3:s4;
            off = i & 65535;
        } else if (i < 720896){
            s = s5; off = i - 327680;
        } else {
            s = s6; off = i - 720896;
        }
        f32x4 v = *(const f32x4*)(s + off);
        ushort4_t o;
        #pragma unroll
        for (int e = 0; e < 4; e++) o[e] = f2bf(v[e]);
        *(ushort4_t*)(Wb + i) = o;
    } else if (bid < 864){
        int i = (bid - 832)*256 + tid;
        float x = xyzB[i*3], y = xyzB[i*3+1], z = xyzB[i*3+2];
        f32x4 o;
        o[0] = -2.f*x; o[1] = -2.f*y; o[2] = -2.f*z;
        o[3] = x*x + y*y + z*z;
        PB[i] = o;
    } else if (bid < 866){
        unsigned int* hist = (unsigned int*)smem;
        unsigned int* wsum = (unsigned int*)(smem + 4096);
        const int b = bid - 864;
        const int wv = tid >> 6, lane = tid & 63;
        for (int i = tid; i < 1024; i += 256) hist[i] = 0u;
        __syncthreads();
        unsigned int code[16];
        #pragma unroll
        for (int i = 0; i < 16; i++){
            const int n = tid + i*256;
            const float* pp = xyzA + (size_t)((b<<12) + n)*3;
            int qx = (int)fminf(fmaxf((pp[0] + 5.f)*1.6f, 0.f), 15.f);
            int qy = (int)fminf(fmaxf((pp[1] + 5.f)*0.8f, 0.f), 7.f);
            int qz = (int)fminf(fmaxf((pp[2] + 5.f)*0.8f, 0.f), 7.f);
            unsigned int c = (unsigned int)((qx & 1) | ((qz & 1) << 1) | ((qy & 1) << 2)
                           | (((qx >> 1) & 1) << 3) | (((qz >> 1) & 1) << 4) | (((qy >> 1) & 1) << 5)
                           | (((qx >> 2) & 1) << 6) | (((qz >> 2) & 1) << 7) | (((qy >> 2) & 1) << 8)
                           | (((qx >> 3) & 1) << 9));
            code[i] = c;
            atomicAdd(&hist[c], 1u);
        }
        __syncthreads();
        unsigned int loc[4], t4 = 0;
        #pragma unroll
        for (int j = 0; j < 4; j++){ loc[j] = hist[tid*4 + j]; t4 += loc[j]; }
        unsigned int sc = t4;
        #pragma unroll
        for (int off = 1; off < 64; off <<= 1){
            unsigned int o = __shfl_up(sc, off, 64);
            if (lane >= off) sc += o;
        }
        if (lane == 63) wsum[wv] = sc;
        __syncthreads();
        unsigned int wb = 0;
        #pragma unroll
        for (int j = 0; j < 4; j++) if (j < wv) wb += wsum[j];
        unsigned int base = wb + sc - t4;
        #pragma unroll
        for (int j = 0; j < 4; j++){ hist[tid*4 + j] = base; base += loc[j]; }
        __syncthreads();
        #pragma unroll
        for (int i = 0; i < 16; i++){
            const int n = tid + i*256;
            unsigned int pos = atomicAdd(&hist[code[i]], 1u);
            order[(b<<12) + pos] = (b<<12) | n;
        }
    } else if (bid < 1122){
        float (*tile)[257] = (float(*)[257])smem;
        float (*ps)[32]    = (float(*)[32])(smem + 32896);
        float (*pq)[32]    = (float(*)[32])(smem + 33920);
        float (*st)[32]    = (float(*)[32])(smem + 34944);
        const int nx = tid & 31, cy = tid >> 5;
        const int pbase = (bid - 866) * 32;
        const int b = pbase >> 12, n0 = pbase & 4095;
        const float* sp = featA + (size_t)b*C_*N_ + n0;
        #pragma unroll 4
        for (int it = 0; it < 32; it++){
            int c = cy + it*8;
            tile[nx][c] = sp[(size_t)c*N_ + nx];
        }
        __syncthreads();
        {
            float s = 0.f, q = 0.f;
            #pragma unroll 8
            for (int i = 0; i < 32; i++){
                int cc = cy*32 + ((i + cy) & 31);
                float x = tile[nx][cc];
                s += x; q = fmaf(x, x, q);
            }
            ps[cy][nx] = s; pq[cy][nx] = q;
        }
        __syncthreads();
        if (tid < 32){
            float S = 0.f, Q = 0.f;
            #pragma unroll
            for (int j = 0; j < 8; j++){ S += ps[j][tid]; Q += pq[j][tid]; }
            float m = S*(1.f/256.f);
            float v = Q*(1.f/256.f) - m*m;
            st[0][tid] = m; st[1][tid] = rsqrtf(v + 1e-5f);
        }
        __syncthreads();
        const int p = pbase + nx;
        const float m = st[0][nx], r = st[1][nx];
        #pragma unroll
        for (int j = 0; j < 4; j++){
            bf16x8 ob;
            #pragma unroll
            for (int e = 0; e < 8; e++){
                int c = cy*32 + j*8 + e;
                ob[e] = (short)f2bf((tile[nx][c]-m)*r*lnw[c] + lnb[c]);
            }
            *(bf16x8*)(F + (size_t)p*768 + cy*32 + j*8) = ob;
        }
    } else {
        float (*tile)[257] = (float(*)[257])smem;
        const int nx = tid & 31, cy = tid >> 5;
        const int pbase = (bid - 1122) * 32;
        const int b = pbase >> 12, n0 = pbase & 4095;
        const float* sp = featB + (size_t)b*C_*N_ + n0;
        #pragma unroll 4
        for (int it = 0; it < 32; it++){
            int c = cy + it*8;
            tile[nx][c] = sp[(size_t)c*N_ + nx];
        }
        __syncthreads();
        const int p = pbase + nx;
        #pragma unroll
        for (int j = 0; j < 4; j++){
            bf16x8 ob;
            #pragma unroll
            for (int e = 0; e < 8; e++){
                int c = cy*32 + j*8 + e;
                ob[e] = (short)f2bf(tile[nx][c]);
            }
            *(bf16x8*)(XBT + (size_t)p*256 + cy*32 + j*8) = ob;
        }
    }
}

// ---------------- KNN: 2 queries per wave, float-rank threshold ----------------
__global__ __launch_bounds__(256) void k_knn(const float* __restrict__ xyzA,
        const f32x4* __restrict__ PB, int* __restrict__ knn){
    const int wv = threadIdx.x >> 6, lane = threadIdx.x & 63;
    const int q0 = blockIdx.x*8 + wv*2;
    const int b = q0 >> 12;
    const f32x4* pb = PB + ((size_t)b << 12);
    const float ax0 = xyzA[(size_t)q0*3],     ay0 = xyzA[(size_t)q0*3+1],     az0 = xyzA[(size_t)q0*3+2];
    const float ax1 = xyzA[(size_t)(q0+1)*3], ay1 = xyzA[(size_t)(q0+1)*3+1], az1 = xyzA[(size_t)(q0+1)*3+2];

    float dm0 = 3.4e38f, dm1 = 3.4e38f;
    int   mi0 = 0, mi1 = 0;
    #pragma unroll 8
    for (int i = 0; i < 64; i++){
        const int m = i*64 + lane;
        f32x4 c = pb[m];
        float d0 = fmaf(ax0, c[0], fmaf(ay0, c[1], fmaf(az0, c[2], c[3])));
        float d1 = fmaf(ax1, c[0], fmaf(ay1, c[1], fmaf(az1, c[2], c[3])));
        if (d0 < dm0){ dm0 = d0; mi0 = m; }
        if (d1 < dm1){ dm1 = d1; mi1 = m; }
    }
    // float-strict rank of the lane minima (1 bpermute/step/query instead of 2).
    // A lane with rank 31 has 31 strictly-smaller minima + itself => its distance
    // is a valid >= T32 threshold. Ties can make rank 31 vanish -> C<32 -> fallback.
    unsigned int rk0 = 0, rk1 = 0;
    for (int j = 0; j < 64; j++){
        float o0 = __shfl(dm0, j, 64);
        float o1 = __shfl(dm1, j, 64);
        rk0 += (o0 < dm0) ? 1u : 0u;
        rk1 += (o1 < dm1) ? 1u : 0u;
    }
    const unsigned long long key0 = (((unsigned long long)mono(dm0)) << 12) | (unsigned int)mi0;
    const unsigned long long key1 = (((unsigned long long)mono(dm1)) << 12) | (unsigned int)mi1;
    unsigned long long sel0 = (rk0 == 31u) ? key0 : ~0ull;
    unsigned long long sel1 = (rk1 == 31u) ? key1 : ~0ull;
    #pragma unroll
    for (int off = 32; off; off >>= 1){
        unsigned long long o0 = __shfl_xor(sel0, off, 64);
        unsigned long long o1 = __shfl_xor(sel1, off, 64);
        sel0 = o0 < sel0 ? o0 : sel0;
        sel1 = o1 < sel1 ? o1 : sel1;
    }
    const float vf0 = unmono((unsigned int)(sel0 >> 12));
    const float vf1 = unmono((unsigned int)(sel1 >> 12));

    __shared__ unsigned long long cand[8][CAPW];
    __shared__ unsigned int cnt[8];
    const int s0 = wv*2, s1 = wv*2 + 1;
    if (lane == 0){ cnt[s0] = 0u; cnt[s1] = 0u; }
    #pragma unroll 4
    for (int i = 0; i < 64; i++){
        const int m = i*64 + lane;
        f32x4 c = pb[m];
        float d0 = fmaf(ax0, c[0], fmaf(ay0, c[1], fmaf(az0, c[2], c[3])));
        float d1 = fmaf(ax1, c[0], fmaf(ay1, c[1], fmaf(az1, c[2], c[3])));
        if (d0 <= vf0){
            unsigned int slot = atomicAdd(&cnt[s0], 1u);
            if (slot < CAPW)
                cand[s0][slot] = (((unsigned long long)mono(d0)) << 12) | (unsigned int)m;
        }
        if (d1 <= vf1){
            unsigned int slot = atomicAdd(&cnt[s1], 1u);
            if (slot < CAPW)
                cand[s1][slot] = (((unsigned long long)mono(d1)) << 12) | (unsigned int)m;
        }
    }
    {
        const unsigned int C = cnt[s0];
        if (C >= (unsigned)K_ && C <= CAPW){
            for (unsigned int i = lane; i < C; i += 64){
                unsigned long long mk = cand[s0][i];
                unsigned int rank = 0;
                for (unsigned int j = 0; j < C; j++) rank += (cand[s0][j] < mk) ? 1u : 0u;
                if (rank < K_) knn[(size_t)q0*K_ + rank] = (int)(mk & 0xFFFull);
            }
        } else {
            unsigned long long last = 0ull;
            for (int it = 0; it < K_; it++){
                unsigned long long cm = ~0ull;
                #pragma unroll 4
                for (int i = 0; i < 64; i++){
                    const int m = i*64 + lane;
                    f32x4 c = pb[m];
                    float d = fmaf(ax0, c[0], fmaf(ay0, c[1], fmaf(az0, c[2], c[3])));
                    unsigned long long key = (((unsigned long long)mono(d)) << 12) | (unsigned int)m;
                    if (key > last && key < cm) cm = key;
                }
                #pragma unroll
                for (int off = 32; off; off >>= 1){
                    unsigned long long o = __shfl_xor(cm, off, 64);
                    cm = o < cm ? o : cm;
                }
                if (lane == 0) knn[(size_t)q0*K_ + it] = (int)(cm & 0xFFFull);
                last = cm;
            }
        }
    }
    {
        const unsigned int C = cnt[s1];
        if (C >= (unsigned)K_ && C <= CAPW){
            for (unsigned int i = lane; i < C; i += 64){
                unsigned long long mk = cand[s1][i];
                unsigned int rank = 0;
                for (unsigned int j = 0; j < C; j++) rank += (cand[s1][j] < mk) ? 1u : 0u;
                if (rank < K_) knn[(size_t)(q0+1)*K_ + rank] = (int)(mk & 0xFFFull);
            }
        } else {
            unsigned long long last = 0ull;
            for (int it = 0; it < K_; it++){
                unsigned long long cm = ~0ull;
                #pragma unroll 4
                for (int i = 0; i < 64; i++){
                    const int m = i*64 + lane;
                    f32x4 c = pb[m];
                    float d = fmaf(ax1, c[0], fmaf(ay1, c[1], fmaf(az1, c[2], c[3])));
                    unsigned long long key = (((unsigned long long)mono(d)) << 12) | (unsigned int)m;
                    if (key > last && key < cm) cm = key;
                }
                #pragma unroll
                for (int off = 32; off; off >>= 1){
                    unsigned long long o = __shfl_xor(cm, off, 64);
                    cm = o < cm ? o : cm;
                }
                if (lane == 0) knn[(size_t)(q0+1)*K_ + it] = (int)(cm & 0xFFFull);
                last = cm;
            }
        }
    }
}

// ---------------- MFMA GEMM body: 128x64 tile, BK=32, gload_lds double buffer ----
template<int MODE>
__device__ __forceinline__ void gemm_body(
    const unsigned short* __restrict__ X, int ldx,
    const unsigned short* __restrict__ W, int Kin,
    const float* __restrict__ e0, const float* __restrict__ e1, const float* __restrict__ e2,
    unsigned short* __restrict__ Y, int ldy,
    const float* __restrict__ resid, float* __restrict__ out,
    unsigned short (*As)[128*32], unsigned short (*Bs)[64*32], int bx, int by)
{
    const int tid = threadIdx.x, wid = tid >> 6, lane = tid & 63;
    const int lr = lane & 15, lg = lane >> 4;
    const int m0 = bx*128, n0 = by*64;
    const int lrow = lane >> 2, lcol = (lane & 3)*8;

    const unsigned short* Ag0 = X + (size_t)(m0 + wid*32 + lrow)*ldx + lcol;
    const unsigned short* Ag1 = X + (size_t)(m0 + wid*32 + 16 + lrow)*ldx + lcol;
    const unsigned short* Bg0 = W + (size_t)(n0 + wid*16 + lrow)*Kin + lcol;

    f32x4 acc[2][4] = {};
    const int NT = Kin >> 5;
    int buf = 0;
    gload_lds16(Ag0, &As[0][(wid*32)*32]);
    gload_lds16(Ag1, &As[0][(wid*32+16)*32]);
    gload_lds16(Bg0, &Bs[0][(wid*16)*32]);
    __syncthreads();
    for (int kt = 0; kt < NT; kt++){
        if (kt + 1 < NT){
            const int k = (kt+1)*32;
            gload_lds16(Ag0 + k, &As[buf^1][(wid*32)*32]);
            gload_lds16(Ag1 + k, &As[buf^1][(wid*32+16)*32]);
            gload_lds16(Bg0 + k, &Bs[buf^1][(wid*16)*32]);
        }
        bf16x8 a[2], b[4];
        #pragma unroll
        for (int mi = 0; mi < 2; mi++)
            a[mi] = *(const bf16x8*)&As[buf][(wid*32 + mi*16 + lr)*32 + lg*8];
        #pragma unroll
        for (int ni = 0; ni < 4; ni++)
            b[ni] = *(const bf16x8*)&Bs[buf][(ni*16 + lr)*32 + lg*8];
        #pragma unroll
        for (int mi = 0; mi < 2; mi++){
            #pragma unroll
            for (int ni = 0; ni < 4; ni++)
                acc[mi][ni] = __builtin_amdgcn_mfma_f32_16x16x32_bf16(a[mi], b[ni], acc[mi][ni], 0, 0, 0);
        }
        __syncthreads();
        buf ^= 1;
    }
    #pragma unroll
    for (int mi = 0; mi < 2; mi++){
        const int pbase = m0 + wid*32 + mi*16 + lg*4;
        #pragma unroll
        for (int ni = 0; ni < 4; ni++){
            const int o = n0 + ni*16 + lr;
            if (MODE == 0){
                const float* bp = (o < 256) ? e0 : ((o < 512) ? e1 : e2);
                float bias = bp[o & 255];
                #pragma unroll
                for (int r = 0; r < 4; r++)
                    Y[(size_t)(pbase + r)*ldy + o] = f2bf(acc[mi][ni][r] + bias);
            } else if (MODE == 1){
                float sc = e0[o] * 0.9999950000374997f;
                float sh = e1[o];
                #pragma unroll
                for (int r = 0; r < 4; r++){
                    float vv = fmaf(acc[mi][ni][r], sc, sh);
                    Y[(size_t)(pbase + r)*ldy + o] = f2bf(fmaxf(vv, 0.f));
                }
            } else {
                float bias = e0[o];
                const int b = pbase >> 12, nn = pbase & 4095;
                const size_t adr = ((size_t)b*C_ + o)*N_ + nn;
                f32x4 rv = *(const f32x4*)(resid + adr);
                f32x4 ov;
                #pragma unroll
                for (int r = 0; r < 4; r++) ov[r] = acc[mi][ni][r] + bias + rv[r];
                *(f32x4*)(out + adr) = ov;
            }
        }
    }
}

__global__ __launch_bounds__(256) void k_proj(
    const unsigned short* __restrict__ F, const unsigned short* __restrict__ XBT,
    const unsigned short* __restrict__ WQcat, const unsigned short* __restrict__ WKVD,
    const float* __restrict__ bq, const float* __restrict__ bqd,
    const float* __restrict__ bk, const float* __restrict__ bv, const float* __restrict__ bkd,
    unsigned short* __restrict__ QQ, unsigned short* __restrict__ KVD)
{
    __shared__ __align__(16) unsigned short As[2][128*32];
    __shared__ __align__(16) unsigned short Bs[2][64*32];
    if (blockIdx.y < 8)
        gemm_body<0>(F, 768, WQcat, 256, bq, bqd, nullptr, QQ, 512, nullptr, nullptr,
                     As, Bs, blockIdx.x, blockIdx.y);
    else
        gemm_body<0>(XBT, 256, WKVD, 256, bk, bv, bkd, KVD, 768, nullptr, nullptr,
                     As, Bs, blockIdx.x, blockIdx.y - 8);
}

template<int MODE>
__global__ __launch_bounds__(256) void k_gemm(
    const unsigned short* __restrict__ X, int ldx,
    const unsigned short* __restrict__ W, int Kin,
    const float* __restrict__ e0, const float* __restrict__ e1, const float* __restrict__ e2,
    unsigned short* __restrict__ Y, int ldy,
    const float* __restrict__ resid, float* __restrict__ out)
{
    __shared__ __align__(16) unsigned short As[2][128*32];
    __shared__ __align__(16) unsigned short Bs[2][64*32];
    gemm_body<MODE>(X, ldx, W, Kin, e0, e1, e2, Y, ldy, resid, out,
                    As, Bs, blockIdx.x, blockIdx.y);
}

// ---------------- dual-path neighbor attention: row-cooperative, dot2 sim only ----
__global__ __launch_bounds__(128) void k_attn(
    const unsigned short* __restrict__ QQ, const unsigned short* __restrict__ KVD,
    const int* __restrict__ KNN, const int* __restrict__ order,
    const float* __restrict__ lnsw, const float* __restrict__ lnsb,
    const float* __restrict__ lndw, const float* __restrict__ lndb,
    unsigned short* __restrict__ F)
{
    __shared__ int   idx_l[2][32];
    __shared__ float part_l[2][4];

    const int tid = threadIdx.x;
    const int wh = tid >> 6, lane = tid & 63;
    const int bid = blockIdx.x;
    const int xcd = bid & 7, ib = bid >> 3;
    const int batch = xcd & 1, quarter = xcd >> 1;
    const int p = order[(batch << 12) + quarter*1024 + ib];
    const int b = batch;

    if (lane < 32) idx_l[wh][lane] = KNN[(size_t)p*K_ + lane];

    const int tq = lane >> 4, c = lane & 15;

    uint4 qsu;
    float qdf[8];
    {
        const unsigned short* qrow = QQ + (size_t)p*512 + wh*128 + c*8;
        qsu = *(const uint4*)(qrow);
        bf16x8 qd8 = *(const bf16x8*)(qrow + 256);
        #pragma unroll
        for (int e = 0; e < 8; e++) qdf[e] = bf2f((unsigned short)qd8[e]);
    }
    const unsigned short* KB = KVD + (size_t)(b << 12)*768;
    int nbt[8];
    #pragma unroll
    for (int i = 0; i < 8; i++) nbt[i] = idx_l[wh][tq + i*4];

    float s[8];
    {
        uint4 kx[8];
        #pragma unroll
        for (int i = 0; i < 8; i++)
            kx[i] = *(const uint4*)(KB + (size_t)nbt[i]*768 + wh*128 + c*8);
        #pragma unroll
        for (int i = 0; i < 8; i++){
            float a = 0.f;
            DOT2BF(a, qsu.x, kx[i].x); DOT2BF(a, qsu.y, kx[i].y);
            DOT2BF(a, qsu.z, kx[i].z); DOT2BF(a, qsu.w, kx[i].w);
            s[i] = a;
        }
    }
    float t[8];
    {
        bf16x8 dx[8];
        #pragma unroll
        for (int i = 0; i < 8; i++)
            dx[i] = *(const bf16x8*)(KB + (size_t)nbt[i]*768 + 512 + wh*128 + c*8);
        #pragma unroll
        for (int i = 0; i < 8; i++){
            float a = 0.f;
            #pragma unroll
            for (int e = 0; e < 8; e++){
                float df = qdf[e] - bf2f((unsigned short)dx[i][e]);
                a = fmaf(df, df, a);
            }
            t[i] = a;
        }
    }
    bf16x8 vx[8];
    #pragma unroll
    for (int i = 0; i < 8; i++)
        vx[i] = *(const bf16x8*)(KB + (size_t)nbt[i]*768 + 256 + wh*128 + c*8);

    #pragma unroll
    for (int i = 0; i < 8; i++){
        s[i] += __shfl_xor(s[i], 1, 64); s[i] += __shfl_xor(s[i], 2, 64);
        t[i] += __shfl_xor(t[i], 1, 64); t[i] += __shfl_xor(t[i], 2, 64);
    }
    float sim[8], dist[8];
    #pragma unroll
    for (int i = 0; i < 8; i++){
        sim[i]  = s[i] * 0.17677669529663687f;   // 1/sqrt(32)
        dist[i] = sqrtf(t[i]);
    }
    float m1 = sim[0], m2 = dist[0];
    #pragma unroll
    for (int i = 1; i < 8; i++){ m1 = fmaxf(m1, sim[i]); m2 = fmaxf(m2, dist[i]); }
    m1 = fmaxf(m1, __shfl_xor(m1, 16, 64)); m1 = fmaxf(m1, __shfl_xor(m1, 32, 64));
    m2 = fmaxf(m2, __shfl_xor(m2, 16, 64)); m2 = fmaxf(m2, __shfl_xor(m2, 32, 64));
    float e1[8], e2[8], s1 = 0.f, s2 = 0.f;
    #pragma unroll
    for (int i = 0; i < 8; i++){
        e1[i] = __expf(sim[i] - m1);  s1 += e1[i];
        e2[i] = __expf(dist[i] - m2); s2 += e2[i];
    }
    s1 += __shfl_xor(s1, 16, 64); s1 += __shfl_xor(s1, 32, 64);
    s2 += __shfl_xor(s2, 16, 64); s2 += __shfl_xor(s2, 32, 64);
    const float r1i = 1.f / s1, r2i = 1.f / s2;

    float cs[8] = {0,0,0,0,0,0,0,0}, cd[8] = {0,0,0,0,0,0,0,0};
    #pragma unroll
    for (int i = 0; i < 8; i++){
        const float w1 = e1[i] * r1i;
        const float w2 = e2[i] * r2i;
        #pragma unroll
        for (int e = 0; e < 8; e++){
            float vf = bf2f((unsigned short)vx[i][e]);
            cs[e] = fmaf(w1, vf, cs[e]);
            cd[e] = fmaf(w2, vf, cd[e]);
        }
    }
    #pragma unroll
    for (int e = 0; e < 8; e++){
        cs[e] += __shfl_xor(cs[e], 16, 64); cs[e] += __shfl_xor(cs[e], 32, 64);
        cd[e] += __shfl_xor(cd[e], 16, 64); cd[e] += __shfl_xor(cd[e], 32, 64);
    }
    float s1n = 0.f, q1n = 0.f, s2n = 0.f, q2n = 0.f;
    #pragma unroll
    for (int e = 0; e < 8; e++){
        s1n += cs[e]; q1n = fmaf(cs[e], cs[e], q1n);
        s2n += cd[e]; q2n = fmaf(cd[e], cd[e], q2n);
    }
    #pragma unroll
    for (int off = 1; off < 16; off <<= 1){
        s1n += __shfl_xor(s1n, off, 64); q1n += __shfl_xor(q1n, off, 64);
        s2n += __shfl_xor(s2n, off, 64); q2n += __shfl_xor(q2n, off, 64);
    }
    if (lane == 0){
        part_l[wh][0] = s1n; part_l[wh][1] = q1n;
        part_l[wh][2] = s2n; part_l[wh][3] = q2n;
    }
    __syncthreads();
    const float S1 = s1n + part_l[wh^1][0];
    const float Q1 = q1n + part_l[wh^1][1];
    const float S2 = s2n + part_l[wh^1][2];
    const float Q2 = q2n + part_l[wh^1][3];
    const float mm1 = S1*(1.f/256.f), mm2 = S2*(1.f/256.f);
    const float rr1 = rsqrtf(Q1*(1.f/256.f) - mm1*mm1 + 1e-5f);
    const float rr2 = rsqrtf(Q2*(1.f/256.f) - mm2*mm2 + 1e-5f);

    if (tq == 0){
        bf16x8 ob;
        #pragma unroll
        for (int e = 0; e < 8; e++){
            const int cg = wh*128 + c*8 + e;
            ob[e] = (short)f2bf((cs[e]-mm1)*rr1*lnsw[cg] + lnsb[cg]);
        }
        *(bf16x8*)(F + (size_t)p*768 + 256 + wh*128 + c*8) = ob;
    } else if (tq == 1){
        bf16x8 ob;
        #pragma unroll
        for (int e = 0; e < 8; e++){
            const int cg = wh*128 + c*8 + e;
            ob[e] = (short)f2bf((cd[e]-mm2)*rr2*lndw[cg] + lndb[cg]);
        }
        *(bf16x8*)(F + (size_t)p*768 + 512 + wh*128 + c*8) = ob;
    }
}

extern "C" void kernel_launch(void* const* d_in, const int* in_sizes, int n_in,
                              void* d_out, int out_size, void* d_ws, size_t ws_size,
                              hipStream_t stream)
{
    const float* xyzA   = (const float*)d_in[0];
    const float* xyzB   = (const float*)d_in[1];
    const float* featA  = (const float*)d_in[2];
    const float* featB  = (const float*)d_in[3];
    const float* ln_in_w= (const float*)d_in[4];
    const float* ln_in_b= (const float*)d_in[5];
    const float* wq  = (const float*)d_in[6];
    const float* bq  = (const float*)d_in[7];
    const float* wk  = (const float*)d_in[8];
    const float* bk  = (const float*)d_in[9];
    const float* wv  = (const float*)d_in[10];
    const float* bv  = (const float*)d_in[11];
    const float* wqd = (const float*)d_in[12];
    const float* bqd = (const float*)d_in[13];
    const float* wkd = (const float*)d_in[14];
    const float* bkd = (const float*)d_in[15];
    const float* lnsw = (const float*)d_in[16];
    const float* lnsb = (const float*)d_in[17];
    const float* lndw = (const float*)d_in[18];
    const float* lndb = (const float*)d_in[19];
    const float* fw1 = (const float*)d_in[20];
    const float* bng = (const float*)d_in[21];
    const float* bnb = (const float*)d_in[22];
    const float* fw2 = (const float*)d_in[23];
    const float* fb2 = (const float*)d_in[24];
    float* out = (float*)d_out;
    char* ws = (char*)d_ws;

    unsigned short* F    = (unsigned short*)(ws + 0);          // 8192*768 bf16
    unsigned short* XBT  = (unsigned short*)(ws + 12582912);   // 8192*256
    unsigned short* QQ   = (unsigned short*)(ws + 16777216);   // 8192*512
    unsigned short* KVD  = (unsigned short*)(ws + 25165824);   // 8192*768
    unsigned short* Y1   = (unsigned short*)(ws + 37748736);   // 8192*512 ; PB earlier
    f32x4*          PB   = (f32x4*)(ws + 37748736);            // dead before fus1
    int*            KNNi = (int*)(ws + 46137344);              // 8192*32
    int*            ORD  = (int*)(ws + 47185920);              // 8192*4
    unsigned short* Wb   = (unsigned short*)(ws + 47251456);   // 851968 bf16
    unsigned short* WQcat = Wb;                // 512x256
    unsigned short* WKVD  = Wb + 131072;       // 768x256
    unsigned short* W1b   = Wb + 327680;       // 512x768
    unsigned short* W2b   = Wb + 720896;       // 256x512

    k_pre<<<1378, 256, 0, stream>>>(wq, wqd, wk, wv, wkd, fw1, fw2, Wb,
                                    xyzB, PB, xyzA, ORD,
                                    featA, ln_in_w, ln_in_b, F, featB, XBT);
    k_knn<<<1024, 256, 0, stream>>>(xyzA, PB, KNNi);

    k_proj<<<dim3(64,20), 256, 0, stream>>>(F, XBT, WQcat, WKVD, bq, bqd, bk, bv, bkd, QQ, KVD);

    k_attn<<<8192, 128, 0, stream>>>(QQ, KVD, KNNi, ORD, lnsw, lnsb, lndw, lndb, F);

    k_gemm<1><<<dim3(64,8), 256, 0, stream>>>(F,  768, W1b, 768, bng, bnb, nullptr, Y1, 512, nullptr, nullptr);
    k_gemm<2><<<dim3(64,4), 256, 0, stream>>>(Y1, 512, W2b, 512, fb2, nullptr, nullptr, nullptr, 0, featA, out);
}